// Round 7
// baseline (3955.478 us; speedup 1.0000x reference)
//
#include <hip/hip_runtime.h>
#include <hip/hip_bf16.h>

typedef unsigned int u32;
typedef unsigned short u16;
typedef _Float16 f16;
typedef f16 f16x2 __attribute__((ext_vector_type(2)));

#define BB 128
#define TT 512
#define HE 256      // encoder hidden
#define G3E 768
#define HD 512      // decoder hidden (2H)
#define G3D 1536
#define LL 64
#define NDICT 30
#define EMBD 256

__device__ __forceinline__ float fexp2(float v){
#if __has_builtin(__builtin_amdgcn_exp2f)
  return __builtin_amdgcn_exp2f(v);
#else
  return exp2f(v);
#endif
}
__device__ __forceinline__ float frcp(float v){
#if __has_builtin(__builtin_amdgcn_rcpf)
  return __builtin_amdgcn_rcpf(v);
#else
  return 1.f/v;
#endif
}
__device__ __forceinline__ float sigm(float v){
  return frcp(1.f + fexp2(-1.4426950408889634f*v));
}
__device__ __forceinline__ float ftanh(float v){
  float e = fexp2(fminf(v, 40.f)*2.8853901631790583f);
  return (e - 1.f)*frcp(e + 1.f);
}
__device__ __forceinline__ u16 f2bf(float f){
  u32 u = __float_as_uint(f);
  u = (u + 0x7FFFu + ((u >> 16) & 1u)) >> 16;
  return (u16)u;
}
__device__ __forceinline__ float bf2f(u16 h){ return __uint_as_float(((u32)h) << 16); }
__device__ __forceinline__ u32 pkh2(float a, float b){
  u16 lo = __builtin_bit_cast(u16, (f16)a);
  u16 hi = __builtin_bit_cast(u16, (f16)b);
  return (u32)lo | ((u32)hi << 16);
}
__device__ __forceinline__ f16x2 bc2(u32 v){ return __builtin_bit_cast(f16x2, v); }

__device__ __forceinline__ void unp8(uint4 v, float* d){
  d[0]=__uint_as_float((v.x&0xffffu)<<16); d[1]=__uint_as_float(v.x&0xffff0000u);
  d[2]=__uint_as_float((v.y&0xffffu)<<16); d[3]=__uint_as_float(v.y&0xffff0000u);
  d[4]=__uint_as_float((v.z&0xffffu)<<16); d[5]=__uint_as_float(v.z&0xffff0000u);
  d[6]=__uint_as_float((v.w&0xffffu)<<16); d[7]=__uint_as_float(v.w&0xffff0000u);
}

__device__ __forceinline__ ushort4 pk4(float a, float b, float c, float d){
  ushort4 r; r.x=f2bf(a); r.y=f2bf(b); r.z=f2bf(c); r.w=f2bf(d); return r;
}

// dot2: acc += w(2xf16) . h(2xf16), f32 accumulate
__device__ __forceinline__ float dot2f(u32 w, f16x2 h, float acc){
#if __has_builtin(__builtin_amdgcn_fdot2)
  return __builtin_amdgcn_fdot2(__builtin_bit_cast(f16x2, w), h, acc, false);
#else
  f16x2 wv = __builtin_bit_cast(f16x2, w);
  acc = fmaf((float)wv.x, (float)h.x, acc);
  return fmaf((float)wv.y, (float)h.y, acc);
#endif
}
__device__ __forceinline__ void dot_u4(uint4 wv, uint4 hv, float& acc){
  acc = dot2f(wv.x, bc2(hv.x), acc);
  acc = dot2f(wv.y, bc2(hv.y), acc);
  acc = dot2f(wv.z, bc2(hv.z), acc);
  acc = dot2f(wv.w, bc2(hv.w), acc);
}

// 16-FMA inner step for the 64x64-tile GEMMs (A_s/B_s are [32][68] k-major)
#define INNER16(Q0,Q1)                                              \
  _Pragma("unroll 8")                                               \
  for (int k = 0; k < 32; ++k){                                     \
    float4 a4 = *(const float4*)&A_s[k*68 + (Q0)*4];                \
    float4 b4 = *(const float4*)&B_s[k*68 + (Q1)*4];                \
    acc[0] =fmaf(a4.x,b4.x,acc[0]);  acc[1] =fmaf(a4.x,b4.y,acc[1]); \
    acc[2] =fmaf(a4.x,b4.z,acc[2]);  acc[3] =fmaf(a4.x,b4.w,acc[3]); \
    acc[4] =fmaf(a4.y,b4.x,acc[4]);  acc[5] =fmaf(a4.y,b4.y,acc[5]); \
    acc[6] =fmaf(a4.y,b4.z,acc[6]);  acc[7] =fmaf(a4.y,b4.w,acc[7]); \
    acc[8] =fmaf(a4.z,b4.x,acc[8]);  acc[9] =fmaf(a4.z,b4.y,acc[9]); \
    acc[10]=fmaf(a4.z,b4.z,acc[10]); acc[11]=fmaf(a4.z,b4.w,acc[11]);\
    acc[12]=fmaf(a4.w,b4.x,acc[12]); acc[13]=fmaf(a4.w,b4.y,acc[13]);\
    acc[14]=fmaf(a4.w,b4.z,acc[14]); acc[15]=fmaf(a4.w,b4.w,acc[15]);\
  }

// ---------- prep: generic transpose  dst[c*R + r] = src[r*C + c] ----------
__global__ __launch_bounds__(256) void k_transpose(const float* __restrict__ src,
                                                   float* __restrict__ dst, int R, int C){
  int idx = blockIdx.x*256 + threadIdx.x;
  if (idx < R*C){
    int r = idx / C, c = idx - r*C;
    dst[(size_t)c*R + r] = src[idx];
  }
}

// ---------- prep: encoder Whh -> f16 chunk-major [dir][i 32][j 768] uint4 ----------
__global__ __launch_bounds__(256) void k_prep_wenc(const float* __restrict__ WF,
                                                   const float* __restrict__ WB,
                                                   uint4* __restrict__ dst){
  int idx = blockIdx.x*256 + threadIdx.x;   // 49152 = 2*32*768
  int dir = idx / 24576, rem = idx - dir*24576;
  int i = rem / 768, j = rem - i*768;
  const float* s = (dir ? WB : WF) + (size_t)j*HE + i*8;
  uint4 v; v.x=pkh2(s[0],s[1]); v.y=pkh2(s[2],s[3]); v.z=pkh2(s[4],s[5]); v.w=pkh2(s[6],s[7]);
  dst[idx] = v;
}

// ---------- prep: decoder Whh -> f16 streamed layout [i 96][t 1024] uint4 ----------
// t: jr=t&511, ch=t>>9. i<32: gate r row jr, cols ch*256+i*8.
// i in [32,96): g2=(i-32)>>5, k=(i-32)&31: row (1+g2)*512+jr, cols ch*256+k*8.
__global__ __launch_bounds__(256) void k_prep_wdec(const float* __restrict__ src,
                                                   uint4* __restrict__ dst){
  int idx = blockIdx.x*256 + threadIdx.x;   // 98304 = 96*1024
  int i = idx >> 10, t = idx & 1023;
  int jr = t & 511, ch = t >> 9;
  int row, col;
  if (i < 32){ row = jr; col = ch*256 + i*8; }
  else { int i2 = i - 32; int g2 = i2 >> 5, k = i2 & 31;
         row = (1+g2)*512 + jr; col = ch*256 + k*8; }
  const float* s = src + (size_t)row*HD + col;
  uint4 v; v.x=pkh2(s[0],s[1]); v.y=pkh2(s[2],s[3]); v.z=pkh2(s[4],s[5]); v.w=pkh2(s[6],s[7]);
  dst[idx] = v;
}

// ---------- prep: gi[v][g] = emb[v]@dWih[g] + bih[g] ----------
__global__ __launch_bounds__(256) void k_gi_tab(const float* __restrict__ emb,
                                                const float* __restrict__ Wih,
                                                const float* __restrict__ bih,
                                                float* __restrict__ gi){
  int v = blockIdx.x, gy = blockIdx.y;   // grid (30, 6)
  int g = gy*256 + threadIdx.x;
  __shared__ float e_s[EMBD];
  if (threadIdx.x < EMBD) e_s[threadIdx.x] = emb[(size_t)v*EMBD + threadIdx.x];
  __syncthreads();
  const float4* w4 = (const float4*)(Wih + (size_t)g*EMBD);
  float acc = 0.f;
  #pragma unroll 8
  for (int k = 0; k < EMBD/4; ++k){
    float4 w = w4[k];
    float4 h = *(const float4*)&e_s[k*4];
    acc = fmaf(w.x,h.x,fmaf(w.y,h.y,fmaf(w.z,h.z,fmaf(w.w,h.w,acc))));
  }
  gi[(size_t)v*G3D + g] = acc + bih[g];
}

// ---------- encoder: one block per (batch, direction); weights in VGPRs ----------
__global__ __launch_bounds__(768, 3) void k_enc_p(
    const float* __restrict__ x,
    const uint4* __restrict__ Wp,               // [2][32][768] uint4, chunk-major
    const float* __restrict__ WihF, const float* __restrict__ WihB,
    const float* __restrict__ bihF, const float* __restrict__ bhhF,
    const float* __restrict__ bihB, const float* __restrict__ bhhB,
    u16* __restrict__ enc_out, float* __restrict__ h0out)
{
  const int b   = blockIdx.x >> 1;
  const int dir = blockIdx.x & 1;
  const int j   = threadIdx.x;
  const float* Wih = dir ? WihB : WihF;
  const float* bih = dir ? bihB : bihF;
  const float* bhh = dir ? bhhB : bhhF;

  __shared__ __align__(16) f16 h_lds[HE];   // 512 B
  __shared__ float gh[G3E];                 // 3 KB
  __shared__ float wv0[G3E], wv1[G3E], bis[G3E], bhs[G3E];  // 12 KB

  // Whh row j -> 32 uint4 (128 VGPRs), coalesced chunk-major load
  uint4 w[32];
  {
    const uint4* wsrc = Wp + (size_t)dir*24576 + j;
    #pragma unroll
    for (int i = 0; i < 32; ++i) w[i] = wsrc[(size_t)i*768];
  }
  wv0[j] = Wih[j*2+0]; wv1[j] = Wih[j*2+1];
  bis[j] = bih[j];     bhs[j] = bhh[j];
  if (j < HE) h_lds[j] = (f16)0.f;
  float h_own = 0.f;
  __syncthreads();

  for (int t = 0; t < TT; ++t){
    const int tt = dir ? (TT-1-t) : t;
    // prefetch x for this step (used after barrier; latency hides under dot)
    const float x0 = x[((size_t)b*TT + tt)*2 + 0];
    const float x1 = x[((size_t)b*TT + tt)*2 + 1];

    // gh[j] = Whh[j,:] . h  (4 accumulators, b128 broadcast h reads)
    float a0=0.f, a1=0.f, a2=0.f, a3=0.f;
    const uint4* hv = (const uint4*)h_lds;
    #pragma unroll
    for (int i = 0; i < 32; ++i){
      uint4 h4 = hv[i];
      uint4 wi = w[i];
      a0 = dot2f(wi.x, bc2(h4.x), a0);
      a1 = dot2f(wi.y, bc2(h4.y), a1);
      a2 = dot2f(wi.z, bc2(h4.z), a2);
      a3 = dot2f(wi.w, bc2(h4.w), a3);
    }
    gh[j] = (a0+a1)+(a2+a3);
    __syncthreads();
    if (j < HE){
      float gr = wv0[j]*x0 + wv1[j]*x1 + bis[j] + gh[j] + bhs[j];
      float gz = wv0[j+HE]*x0 + wv1[j+HE]*x1 + bis[j+HE] + gh[j+HE] + bhs[j+HE];
      float r = sigm(gr), z = sigm(gz);
      float gin = wv0[j+2*HE]*x0 + wv1[j+2*HE]*x1 + bis[j+2*HE];
      float n = ftanh(gin + r*(gh[j+2*HE] + bhs[j+2*HE]));
      float hnew = (1.f - z)*n + z*h_own;
      h_own = hnew;
      h_lds[j] = (f16)hnew;
      enc_out[((size_t)b*TT + tt)*HD + dir*HE + j] = f2bf(hnew);
    }
    __syncthreads();
  }
  if (j < HE) h0out[(size_t)b*HD + dir*HE + j] = h_own;
}

// ---------- decoder recurrence: persistent, 128 blocks x 1 batch, 64 steps ----------
// 512 threads (8 waves), 1 block/CU -> VGPR cap >=128, demand ~75 (no spill).
// Thread jr owns gate rows {jr, jr+512, jr+1024}, ALL 512 cols -> complete
// r/z/n pre-activations per thread: no partial-sum LDS, 1 barrier/step.
// Weights streamed from L2 (1.5 MB resident/XCD), 6+6 uint4 double buffer.
__global__ __launch_bounds__(512, 2) void k_dec_p(
    const int* __restrict__ tgt, const float* __restrict__ gi_tab,
    const uint4* __restrict__ Ws, const float* __restrict__ bhh,
    const float* __restrict__ h0, float* __restrict__ Hall)
{
  const int b = blockIdx.x;
  const int jr = threadIdx.x;
  __shared__ __align__(16) f16 h_lds[2][HD];   // 2 KB, double-buffered
  __shared__ int tok_s[LL];

  if (jr < LL) tok_s[jr] = (jr == 0) ? 1 : tgt[(size_t)b*LL + jr - 1];
  const float bh0 = bhh[jr], bh1 = bhh[HD+jr], bh2 = bhh[2*HD+jr];
  float h_own = h0[(size_t)b*HD + jr];
  h_lds[0][jr] = (f16)h_own;
  __syncthreads();

  const uint4* wp = Ws + jr;
  int cur = 0;
  for (int l = 0; l < LL; ++l){
    // prefetch gi (hides under dot phase)
    const int tok = tok_s[l];
    const float* gp = gi_tab + (size_t)tok*G3D + jr;
    const float gi0 = gp[0], gi1 = gp[HD], gi2 = gp[2*HD];
    const uint4* hv = (const uint4*)h_lds[cur];

    float ar = 0.f, az = 0.f, an = 0.f;
    uint4 bufA[6], bufB[6];
    // chunk k (k=0..31): rows {r,z,n} x col-halves {0,1}
    #define LOADC(k, buf) {                              \
      buf[0] = wp[(size_t)(k)*1024];                     \
      buf[1] = wp[(size_t)((k)+32)*1024];                \
      buf[2] = wp[(size_t)((k)+64)*1024];                \
      buf[3] = wp[(size_t)(k)*1024 + 512];               \
      buf[4] = wp[(size_t)((k)+32)*1024 + 512];          \
      buf[5] = wp[(size_t)((k)+64)*1024 + 512]; }
    #define DOTC(k, buf) {                               \
      uint4 hA = hv[(k)], hB = hv[32+(k)];               \
      dot_u4(buf[0], hA, ar); dot_u4(buf[3], hB, ar);    \
      dot_u4(buf[1], hA, az); dot_u4(buf[4], hB, az);    \
      dot_u4(buf[2], hA, an); dot_u4(buf[5], hB, an); }
    #define STEP2(k) LOADC((k)+1, bufB) DOTC((k), bufA) \
                     LOADC((k)+2, bufA) DOTC((k)+1, bufB)
    LOADC(0, bufA)
    STEP2(0)  STEP2(2)  STEP2(4)  STEP2(6)
    STEP2(8)  STEP2(10) STEP2(12) STEP2(14)
    STEP2(16) STEP2(18) STEP2(20) STEP2(22)
    STEP2(24) STEP2(26) STEP2(28)
    LOADC(31, bufB)
    DOTC(30, bufA)
    DOTC(31, bufB)
    #undef LOADC
    #undef DOTC
    #undef STEP2

    float r = sigm(gi0 + ar + bh0);
    float z = sigm(gi1 + az + bh1);
    float n = ftanh(gi2 + r*(an + bh2));
    float hnew = (1.f - z)*n + z*h_own;
    h_own = hnew;
    h_lds[cur^1][jr] = (f16)hnew;
    Hall[((size_t)l*BB + b)*HD + jr] = hnew;
    cur ^= 1;
    __syncthreads();
  }
}

// ---------- Q = Hall @ WqT + bq -> bf16 ; grid (128 rt, 8 nt) ----------
__global__ __launch_bounds__(256) void k_query(const float* __restrict__ Hall,
                                               const float* __restrict__ WqT,
                                               const float* __restrict__ bq,
                                               u16* __restrict__ Qbf){
  const int rt = blockIdx.x, nt = blockIdx.y;
  const int tid = threadIdx.x;
  __shared__ float A_s[32*68];
  __shared__ float B_s[32*68];
  const int rq = tid >> 4, nq = tid & 15;
  const int i = tid >> 2, jj = tid & 3;
  const int i2 = tid >> 3, jj2 = tid & 7;
  float acc[16] = {};
  for (int kc = 0; kc < 16; ++kc){
    __syncthreads();
    {
      const float* src = Hall + (size_t)(rt*64 + i)*HD + kc*32 + jj*8;
      float4 v0 = *(const float4*)src, v1 = *(const float4*)(src+4);
      A_s[(jj*8+0)*68+i]=v0.x; A_s[(jj*8+1)*68+i]=v0.y;
      A_s[(jj*8+2)*68+i]=v0.z; A_s[(jj*8+3)*68+i]=v0.w;
      A_s[(jj*8+4)*68+i]=v1.x; A_s[(jj*8+5)*68+i]=v1.y;
      A_s[(jj*8+6)*68+i]=v1.z; A_s[(jj*8+7)*68+i]=v1.w;
    }
    {
      const float* src = WqT + (size_t)(kc*32 + i2)*HD + nt*64 + jj2*8;
      *(float4*)&B_s[i2*68 + jj2*8]     = *(const float4*)src;
      *(float4*)&B_s[i2*68 + jj2*8 + 4] = *(const float4*)(src+4);
    }
    __syncthreads();
    INNER16(rq, nq)
  }
  const int n0 = nt*64 + nq*4;
  float4 bv = *(const float4*)&bq[n0];
  #pragma unroll
  for (int r = 0; r < 4; ++r){
    u16* dst = Qbf + (size_t)(rt*64 + rq*4 + r)*HD + n0;
    *(ushort4*)dst = pk4(acc[r*4+0]+bv.x, acc[r*4+1]+bv.y,
                         acc[r*4+2]+bv.z, acc[r*4+3]+bv.w);
  }
}

// ---------- S[b][l][t] = Q[b,l,:] . enc[b,t,:] ; grid (128 b, 8 tt) ----------
__global__ __launch_bounds__(256) void k_scores(const u16* __restrict__ Qbf,
                                                const u16* __restrict__ enc,
                                                float* __restrict__ Sbuf){
  const int bI = blockIdx.x, tt = blockIdx.y;
  const int tid = threadIdx.x;
  __shared__ float A_s[32*68];
  __shared__ float B_s[32*68];
  const int lq = tid >> 4, tq = tid & 15;
  const int i = tid >> 2, jj = tid & 3;
  float acc[16] = {};
  for (int kc = 0; kc < 16; ++kc){
    __syncthreads();
    float tmp[8];
    {
      uint4 va = *(const uint4*)(Qbf + ((size_t)i*BB + bI)*HD + kc*32 + jj*8);
      unp8(va, tmp);
      #pragma unroll
      for (int m = 0; m < 8; ++m) A_s[(jj*8+m)*68 + i] = tmp[m];
    }
    {
      uint4 vb = *(const uint4*)(enc + ((size_t)bI*TT + tt*64 + i)*HD + kc*32 + jj*8);
      unp8(vb, tmp);
      #pragma unroll
      for (int m = 0; m < 8; ++m) B_s[(jj*8+m)*68 + i] = tmp[m];
    }
    __syncthreads();
    INNER16(lq, tq)
  }
  #pragma unroll
  for (int r = 0; r < 4; ++r){
    float4 o = make_float4(acc[r*4+0],acc[r*4+1],acc[r*4+2],acc[r*4+3]);
    *(float4*)&Sbuf[((size_t)bI*LL + lq*4+r)*TT + tt*64 + tq*4] = o;
  }
}

// ---------- row softmax over t: P bf16 ; grid 8192 x 64 ----------
__global__ __launch_bounds__(64) void k_softmax(const float* __restrict__ Sbuf,
                                                u16* __restrict__ Pbf){
  const int row = blockIdx.x;
  const int lane = threadIdx.x;
  const float* s = Sbuf + (size_t)row*TT;
  float v[8]; float m = -1e30f;
  #pragma unroll
  for (int i = 0; i < 8; ++i){ v[i] = s[lane + i*64]; m = fmaxf(m, v[i]); }
  #pragma unroll
  for (int o = 32; o; o >>= 1) m = fmaxf(m, __shfl_xor(m, o));
  float Z = 0.f;
  #pragma unroll
  for (int i = 0; i < 8; ++i){ v[i] = fexp2(1.4426950408889634f*(v[i] - m)); Z += v[i]; }
  #pragma unroll
  for (int o = 32; o; o >>= 1) Z += __shfl_xor(Z, o);
  float inv = frcp(Z);
  u16* p = Pbf + (size_t)row*TT;
  #pragma unroll
  for (int i = 0; i < 8; ++i) p[lane + i*64] = f2bf(v[i]*inv);
}

// ---------- attn[b][t][l] = f32(P[b][l][t]) ; grid (128 b, 8 tt) ----------
__global__ __launch_bounds__(256) void k_attn_tr(const u16* __restrict__ Pbf,
                                                 float* __restrict__ att){
  const int bI = blockIdx.x, tt = blockIdx.y;
  const int tid = threadIdx.x;
  __shared__ u16 tile[64][72];
  {
    const int i = tid >> 2, jj = tid & 3;
    #pragma unroll
    for (int rep = 0; rep < 2; ++rep){
      int ch = jj + rep*4;
      uint4 v = *(const uint4*)(Pbf + ((size_t)bI*LL + i)*TT + tt*64 + ch*8);
      *(uint4*)&tile[i][ch*8] = v;
    }
  }
  __syncthreads();
  const int t = tid >> 2, jl = tid & 3;
  #pragma unroll
  for (int rep = 0; rep < 4; ++rep){
    int l0 = jl*16 + rep*4;
    float4 o;
    o.x = bf2f(tile[l0+0][t]); o.y = bf2f(tile[l0+1][t]);
    o.z = bf2f(tile[l0+2][t]); o.w = bf2f(tile[l0+3][t]);
    *(float4*)&att[((size_t)bI*TT + tt*64 + t)*LL + l0] = o;
  }
}

// ---------- ctx[l*128+b][n] = P[b,l,:] @ enc[b,:,n] -> bf16 ; grid (128 b, 8 nt) ----------
__global__ __launch_bounds__(256) void k_ctx(const u16* __restrict__ Pbf,
                                             const u16* __restrict__ enc,
                                             u16* __restrict__ ctxb){
  const int bI = blockIdx.x, nt = blockIdx.y;
  const int tid = threadIdx.x;
  __shared__ float A_s[32*68];
  __shared__ float B_s[32*68];
  const int lq = tid >> 4, nq = tid & 15;
  const int i = tid >> 2, jj = tid & 3;
  const int i2 = tid >> 3, jj2 = tid & 7;
  float acc[16] = {};
  for (int tc = 0; tc < 16; ++tc){
    __syncthreads();
    {
      float tmp[8];
      uint4 va = *(const uint4*)(Pbf + ((size_t)bI*LL + i)*TT + tc*32 + jj*8);
      unp8(va, tmp);
      #pragma unroll
      for (int m = 0; m < 8; ++m) A_s[(jj*8+m)*68 + i] = tmp[m];
    }
    {
      float tmp[8];
      uint4 vb = *(const uint4*)(enc + ((size_t)bI*TT + tc*32 + i2)*HD + nt*64 + jj2*8);
      unp8(vb, tmp);
      *(float4*)&B_s[i2*68 + jj2*8]     = make_float4(tmp[0],tmp[1],tmp[2],tmp[3]);
      *(float4*)&B_s[i2*68 + jj2*8 + 4] = make_float4(tmp[4],tmp[5],tmp[6],tmp[7]);
    }
    __syncthreads();
    INNER16(lq, nq)
  }
  const int n0 = nt*64 + nq*4;
  #pragma unroll
  for (int r = 0; r < 4; ++r){
    int ll = lq*4 + r;
    u16* dst = ctxb + ((size_t)ll*BB + bI)*HD + n0;
    *(ushort4*)dst = pk4(acc[r*4+0], acc[r*4+1], acc[r*4+2], acc[r*4+3]);
  }
}

// ---------- o = [Hall|ctx] @ WcT + bc ; grid (128 rt, 4 nt) ----------
__global__ __launch_bounds__(256) void k_outc(const float* __restrict__ Hall,
                                              const u16* __restrict__ ctxb,
                                              const float* __restrict__ WcT,
                                              const float* __restrict__ bc,
                                              float* __restrict__ obuf){
  const int rt = blockIdx.x, nt = blockIdx.y;
  const int tid = threadIdx.x;
  __shared__ float A_s[32*68];
  __shared__ float B_s[32*68];
  const int rq = tid >> 4, nq = tid & 15;
  const int i = tid >> 2, jj = tid & 3;
  const int i2 = tid >> 3, jj2 = tid & 7;
  float acc[16] = {};
  for (int kc = 0; kc < 32; ++kc){
    __syncthreads();
    if (kc < 16){
      const float* src = Hall + (size_t)(rt*64 + i)*HD + kc*32 + jj*8;
      float4 v0 = *(const float4*)src, v1 = *(const float4*)(src+4);
      A_s[(jj*8+0)*68+i]=v0.x; A_s[(jj*8+1)*68+i]=v0.y;
      A_s[(jj*8+2)*68+i]=v0.z; A_s[(jj*8+3)*68+i]=v0.w;
      A_s[(jj*8+4)*68+i]=v1.x; A_s[(jj*8+5)*68+i]=v1.y;
      A_s[(jj*8+6)*68+i]=v1.z; A_s[(jj*8+7)*68+i]=v1.w;
    } else {
      float tmp[8];
      uint4 v = *(const uint4*)(ctxb + (size_t)(rt*64 + i)*HD + (kc-16)*32 + jj*8);
      unp8(v, tmp);
      #pragma unroll
      for (int m = 0; m < 8; ++m) A_s[(jj*8+m)*68 + i] = tmp[m];
    }
    {
      const float* src = WcT + (size_t)(kc*32 + i2)*256 + nt*64 + jj2*8;
      *(float4*)&B_s[i2*68 + jj2*8]     = *(const float4*)src;
      *(float4*)&B_s[i2*68 + jj2*8 + 4] = *(const float4*)(src+4);
    }
    __syncthreads();
    INNER16(rq, nq)
  }
  const int n0 = nt*64 + nq*4;
  float4 bv = *(const float4*)&bc[n0];
  #pragma unroll
  for (int r = 0; r < 4; ++r){
    float4 o = make_float4(acc[r*4+0]+bv.x, acc[r*4+1]+bv.y,
                           acc[r*4+2]+bv.z, acc[r*4+3]+bv.w);
    *(float4*)&obuf[(size_t)(rt*64 + rq*4 + r)*256 + n0] = o;
  }
}

// ---------- logits = o @ Wf^T + bf ; grid 128 ----------
__global__ __launch_bounds__(256) void k_fc(const float* __restrict__ obuf,
                                            const float* __restrict__ Wf,
                                            const float* __restrict__ bfv,
                                            float* __restrict__ out_vec){
  const int rt = blockIdx.x;
  const int tid = threadIdx.x;
  __shared__ float w_s[30*260];
  for (int rr = 0; rr < 30; ++rr) w_s[rr*260 + tid] = Wf[(size_t)rr*256 + tid];
  __syncthreads();
  const int rl = tid >> 2, dq = tid & 3;
  const int r = rt*64 + rl;
  float acc[8] = {};
  for (int k = 0; k < 256; k += 4){
    float4 o4 = *(const float4*)&obuf[(size_t)r*256 + k];
    #pragma unroll
    for (int jq = 0; jq < 8; ++jq){
      int d = dq*8 + jq;
      if (d < 30){
        float4 w4 = *(const float4*)&w_s[d*260 + k];
        acc[jq] = fmaf(o4.x,w4.x,fmaf(o4.y,w4.y,fmaf(o4.z,w4.z,fmaf(o4.w,w4.w,acc[jq]))));
      }
    }
  }
  const int b = r & 127, l = r >> 7;
  #pragma unroll
  for (int jq = 0; jq < 8; ++jq){
    int d = dq*8 + jq;
    if (d < 30) out_vec[((size_t)b*LL + l)*NDICT + d] = acc[jq] + bfv[d];
  }
}

__global__ __launch_bounds__(256) void k_copy(const float* __restrict__ src,
                                              float* __restrict__ dst, int n){
  int i = blockIdx.x*256 + threadIdx.x;
  if (i < n) dst[i] = src[i];
}

extern "C" void kernel_launch(void* const* d_in, const int* in_sizes, int n_in,
                              void* d_out, int out_size, void* d_ws, size_t ws_size,
                              hipStream_t stream)
{
  const float* x     = (const float*)d_in[0];
  const int*   tgt   = (const int*)  d_in[1];
  const float* eWihF = (const float*)d_in[2];
  const float* eWhhF = (const float*)d_in[3];
  const float* ebihF = (const float*)d_in[4];
  const float* ebhhF = (const float*)d_in[5];
  const float* eWihB = (const float*)d_in[6];
  const float* eWhhB = (const float*)d_in[7];
  const float* ebihB = (const float*)d_in[8];
  const float* ebhhB = (const float*)d_in[9];
  const float* emb   = (const float*)d_in[10];
  const float* dWih  = (const float*)d_in[11];
  const float* dWhh  = (const float*)d_in[12];
  const float* dbih  = (const float*)d_in[13];
  const float* dbhh  = (const float*)d_in[14];
  const float* Wq    = (const float*)d_in[15];
  const float* bq    = (const float*)d_in[16];
  const float* Wc    = (const float*)d_in[17];
  const float* bc    = (const float*)d_in[18];
  const float* Wf    = (const float*)d_in[19];
  const float* bfv   = (const float*)d_in[20];

  char* w = (char*)d_ws;
  uint4* Wpenc = (uint4*)w; w += 786432;     // [2][32][768] uint4 f16
  uint4* Wpdec = (uint4*)w; w += 1572864;    // [96][1024] uint4 f16 (r | z | n)
  float* WqT   = (float*)w; w += 1048576;
  float* WcT   = (float*)w; w += 1048576;
  float* gi_t  = (float*)w; w += 184320;
  float* h0buf = (float*)w; w += 262144;
  float* Hall  = (float*)w; w += 16777216;
  u16*   Qbf   = (u16*)w;                    // aliased: Pbf reuses after k_scores
  u16*   Pbf   = (u16*)w; w += 8388608;
  float* Sbuf  = (float*)w;                  // aliased over (ctxb | obuf)
  u16*   ctxb  = (u16*)w; w += 8388608;
  float* obuf  = (float*)w; w += 8388608;
  u16*   encb  = (u16*)w; w += 67108864;

  float* out     = (float*)d_out;
  float* out_vec = out;                              // [128][64][30]
  float* out_hT  = out + (size_t)BB*LL*NDICT;        // [1][128][512]
  float* out_att = out_hT + (size_t)BB*HD;           // [128][512][64]

  // prep
  k_prep_wenc<<<192, 256, 0, stream>>>(eWhhF, eWhhB, Wpenc);
  k_prep_wdec<<<384, 256, 0, stream>>>(dWhh, Wpdec);
  k_transpose<<<(HD*HD+255)/256, 256, 0, stream>>>(Wq, WqT, HD, HD);
  k_transpose<<<(256*1024+255)/256, 256, 0, stream>>>(Wc, WcT, 256, 1024);
  k_gi_tab<<<dim3(NDICT, 6), 256, 0, stream>>>(emb, dWih, dbih, gi_t);

  // encoder: 256 independent recurrences, weights register-resident
  k_enc_p<<<BB*2, G3E, 0, stream>>>(x, Wpenc, eWihF, eWihB,
                                    ebihF, ebhhF, ebihB, ebhhB, encb, h0buf);

  // decoder recurrence: persistent, 128 blocks x 1 batch, L2-streamed weights
  k_dec_p<<<BB, 512, 0, stream>>>(tgt, gi_t, Wpdec, dbhh, h0buf, Hall);

  // batched post-recurrence pipeline
  k_query<<<dim3(128,8), 256, 0, stream>>>(Hall, WqT, bq, Qbf);
  k_scores<<<dim3(128,8), 256, 0, stream>>>(Qbf, encb, Sbuf);
  k_softmax<<<BB*LL, 64, 0, stream>>>(Sbuf, Pbf);
  k_attn_tr<<<dim3(128,8), 256, 0, stream>>>(Pbf, out_att);
  k_ctx<<<dim3(128,8), 256, 0, stream>>>(Pbf, encb, ctxb);
  k_outc<<<dim3(128,4), 256, 0, stream>>>(Hall, ctxb, WcT, bc, obuf);
  k_fc<<<BB, 256, 0, stream>>>(obuf, Wf, bfv, out_vec);
  k_copy<<<(BB*HD+255)/256, 256, 0, stream>>>(Hall + (size_t)63*BB*HD, out_hT, BB*HD);
}

// Round 8
// 1327.334 us; speedup vs baseline: 2.9800x; 2.9800x over previous
//
#include <hip/hip_runtime.h>
#include <hip/hip_bf16.h>

typedef unsigned int u32;
typedef unsigned short u16;
typedef _Float16 f16;
typedef f16 f16x2 __attribute__((ext_vector_type(2)));

#define BB 128
#define TT 512
#define HE 256      // encoder hidden
#define G3E 768
#define HD 512      // decoder hidden (2H)
#define G3D 1536
#define LL 64
#define NDICT 30
#define EMBD 256

__device__ __forceinline__ float fexp2(float v){
#if __has_builtin(__builtin_amdgcn_exp2f)
  return __builtin_amdgcn_exp2f(v);
#else
  return exp2f(v);
#endif
}
__device__ __forceinline__ float frcp(float v){
#if __has_builtin(__builtin_amdgcn_rcpf)
  return __builtin_amdgcn_rcpf(v);
#else
  return 1.f/v;
#endif
}
__device__ __forceinline__ float sigm(float v){
  return frcp(1.f + fexp2(-1.4426950408889634f*v));
}
__device__ __forceinline__ float ftanh(float v){
  float e = fexp2(fminf(v, 40.f)*2.8853901631790583f);
  return (e - 1.f)*frcp(e + 1.f);
}
__device__ __forceinline__ u16 f2bf(float f){
  u32 u = __float_as_uint(f);
  u = (u + 0x7FFFu + ((u >> 16) & 1u)) >> 16;
  return (u16)u;
}
__device__ __forceinline__ float bf2f(u16 h){ return __uint_as_float(((u32)h) << 16); }
__device__ __forceinline__ u32 pkh2(float a, float b){
  u16 lo = __builtin_bit_cast(u16, (f16)a);
  u16 hi = __builtin_bit_cast(u16, (f16)b);
  return (u32)lo | ((u32)hi << 16);
}
__device__ __forceinline__ f16x2 bc2(u32 v){ return __builtin_bit_cast(f16x2, v); }

__device__ __forceinline__ void unp8(uint4 v, float* d){
  d[0]=__uint_as_float((v.x&0xffffu)<<16); d[1]=__uint_as_float(v.x&0xffff0000u);
  d[2]=__uint_as_float((v.y&0xffffu)<<16); d[3]=__uint_as_float(v.y&0xffff0000u);
  d[4]=__uint_as_float((v.z&0xffffu)<<16); d[5]=__uint_as_float(v.z&0xffff0000u);
  d[6]=__uint_as_float((v.w&0xffffu)<<16); d[7]=__uint_as_float(v.w&0xffff0000u);
}

__device__ __forceinline__ ushort4 pk4(float a, float b, float c, float d){
  ushort4 r; r.x=f2bf(a); r.y=f2bf(b); r.z=f2bf(c); r.w=f2bf(d); return r;
}

// dot2: acc += w(2xf16) . h(2xf16), f32 accumulate
__device__ __forceinline__ float dot2f(u32 w, f16x2 h, float acc){
#if __has_builtin(__builtin_amdgcn_fdot2)
  return __builtin_amdgcn_fdot2(__builtin_bit_cast(f16x2, w), h, acc, false);
#else
  f16x2 wv = __builtin_bit_cast(f16x2, w);
  acc = fmaf((float)wv.x, (float)h.x, acc);
  return fmaf((float)wv.y, (float)h.y, acc);
#endif
}
__device__ __forceinline__ void dot_u4(uint4 wv, uint4 hv, float& acc){
  acc = dot2f(wv.x, bc2(hv.x), acc);
  acc = dot2f(wv.y, bc2(hv.y), acc);
  acc = dot2f(wv.z, bc2(hv.z), acc);
  acc = dot2f(wv.w, bc2(hv.w), acc);
}

// 16-FMA inner step for the 64x64-tile GEMMs (A_s/B_s are [32][68] k-major)
#define INNER16(Q0,Q1)                                              \
  _Pragma("unroll 8")                                               \
  for (int k = 0; k < 32; ++k){                                     \
    float4 a4 = *(const float4*)&A_s[k*68 + (Q0)*4];                \
    float4 b4 = *(const float4*)&B_s[k*68 + (Q1)*4];                \
    acc[0] =fmaf(a4.x,b4.x,acc[0]);  acc[1] =fmaf(a4.x,b4.y,acc[1]); \
    acc[2] =fmaf(a4.x,b4.z,acc[2]);  acc[3] =fmaf(a4.x,b4.w,acc[3]); \
    acc[4] =fmaf(a4.y,b4.x,acc[4]);  acc[5] =fmaf(a4.y,b4.y,acc[5]); \
    acc[6] =fmaf(a4.y,b4.z,acc[6]);  acc[7] =fmaf(a4.y,b4.w,acc[7]); \
    acc[8] =fmaf(a4.z,b4.x,acc[8]);  acc[9] =fmaf(a4.z,b4.y,acc[9]); \
    acc[10]=fmaf(a4.z,b4.z,acc[10]); acc[11]=fmaf(a4.z,b4.w,acc[11]);\
    acc[12]=fmaf(a4.w,b4.x,acc[12]); acc[13]=fmaf(a4.w,b4.y,acc[13]);\
    acc[14]=fmaf(a4.w,b4.z,acc[14]); acc[15]=fmaf(a4.w,b4.w,acc[15]);\
  }

// ---------- prep: generic transpose  dst[c*R + r] = src[r*C + c] ----------
__global__ __launch_bounds__(256) void k_transpose(const float* __restrict__ src,
                                                   float* __restrict__ dst, int R, int C){
  int idx = blockIdx.x*256 + threadIdx.x;
  if (idx < R*C){
    int r = idx / C, c = idx - r*C;
    dst[(size_t)c*R + r] = src[idx];
  }
}

// ---------- prep: encoder Whh -> f16 chunk-major [dir][i 32][j 768] uint4 ----------
__global__ __launch_bounds__(256) void k_prep_wenc(const float* __restrict__ WF,
                                                   const float* __restrict__ WB,
                                                   uint4* __restrict__ dst){
  int idx = blockIdx.x*256 + threadIdx.x;   // 49152 = 2*32*768
  int dir = idx / 24576, rem = idx - dir*24576;
  int i = rem / 768, j = rem - i*768;
  const float* s = (dir ? WB : WF) + (size_t)j*HE + i*8;
  uint4 v; v.x=pkh2(s[0],s[1]); v.y=pkh2(s[2],s[3]); v.z=pkh2(s[4],s[5]); v.w=pkh2(s[6],s[7]);
  dst[idx] = v;
}

// ---------- prep: decoder Whh -> f16 M-parallel layout ----------
// Wd2[cg 64][i 24][lane 64] uint4; lane = kq*8+ci; i = g*8+u.
// value = rows {g*512 + cg*8 + ci}, cols [kq*64 + u*8, +8)
__global__ __launch_bounds__(256) void k_prep_wdec(const float* __restrict__ src,
                                                   uint4* __restrict__ dst){
  int idx = blockIdx.x*256 + threadIdx.x;   // 98304 = 64*24*64
  int lane = idx & 63;
  int ci = lane & 7, kq = lane >> 3;
  int rest = idx >> 6;                      // cg*24 + g*8 + u
  int u = rest & 7, g = (rest >> 3) % 3, cg = rest / 24;
  int row = g*512 + cg*8 + ci;
  int col = kq*64 + u*8;
  const float* s = src + (size_t)row*HD + col;
  uint4 v; v.x=pkh2(s[0],s[1]); v.y=pkh2(s[2],s[3]); v.z=pkh2(s[4],s[5]); v.w=pkh2(s[6],s[7]);
  dst[idx] = v;
}

// ---------- prep: gi[v][g] = emb[v]@dWih[g] + bih[g] ----------
__global__ __launch_bounds__(256) void k_gi_tab(const float* __restrict__ emb,
                                                const float* __restrict__ Wih,
                                                const float* __restrict__ bih,
                                                float* __restrict__ gi){
  int v = blockIdx.x, gy = blockIdx.y;   // grid (30, 6)
  int g = gy*256 + threadIdx.x;
  __shared__ float e_s[EMBD];
  if (threadIdx.x < EMBD) e_s[threadIdx.x] = emb[(size_t)v*EMBD + threadIdx.x];
  __syncthreads();
  const float4* w4 = (const float4*)(Wih + (size_t)g*EMBD);
  float acc = 0.f;
  #pragma unroll 8
  for (int k = 0; k < EMBD/4; ++k){
    float4 w = w4[k];
    float4 h = *(const float4*)&e_s[k*4];
    acc = fmaf(w.x,h.x,fmaf(w.y,h.y,fmaf(w.z,h.z,fmaf(w.w,h.w,acc))));
  }
  gi[(size_t)v*G3D + g] = acc + bih[g];
}

// ---------- prep: h0 f32 -> f16 ----------
__global__ __launch_bounds__(256) void k_h0cvt(const float* __restrict__ src,
                                               f16* __restrict__ dst){
  int i = blockIdx.x*256 + threadIdx.x;   // 65536
  dst[i] = (f16)src[i];
}

// ---------- encoder: one block per (batch, direction); weights in VGPRs ----------
__global__ __launch_bounds__(768, 3) void k_enc_p(
    const float* __restrict__ x,
    const uint4* __restrict__ Wp,               // [2][32][768] uint4, chunk-major
    const float* __restrict__ WihF, const float* __restrict__ WihB,
    const float* __restrict__ bihF, const float* __restrict__ bhhF,
    const float* __restrict__ bihB, const float* __restrict__ bhhB,
    u16* __restrict__ enc_out, float* __restrict__ h0out)
{
  const int b   = blockIdx.x >> 1;
  const int dir = blockIdx.x & 1;
  const int j   = threadIdx.x;
  const float* Wih = dir ? WihB : WihF;
  const float* bih = dir ? bihB : bihF;
  const float* bhh = dir ? bhhB : bhhF;

  __shared__ __align__(16) f16 h_lds[HE];   // 512 B
  __shared__ float gh[G3E];                 // 3 KB
  __shared__ float wv0[G3E], wv1[G3E], bis[G3E], bhs[G3E];  // 12 KB

  // Whh row j -> 32 uint4 (128 VGPRs), coalesced chunk-major load
  uint4 w[32];
  {
    const uint4* wsrc = Wp + (size_t)dir*24576 + j;
    #pragma unroll
    for (int i = 0; i < 32; ++i) w[i] = wsrc[(size_t)i*768];
  }
  wv0[j] = Wih[j*2+0]; wv1[j] = Wih[j*2+1];
  bis[j] = bih[j];     bhs[j] = bhh[j];
  if (j < HE) h_lds[j] = (f16)0.f;
  float h_own = 0.f;
  __syncthreads();

  for (int t = 0; t < TT; ++t){
    const int tt = dir ? (TT-1-t) : t;
    // prefetch x for this step (used after barrier; latency hides under dot)
    const float x0 = x[((size_t)b*TT + tt)*2 + 0];
    const float x1 = x[((size_t)b*TT + tt)*2 + 1];

    // gh[j] = Whh[j,:] . h  (4 accumulators, b128 broadcast h reads)
    float a0=0.f, a1=0.f, a2=0.f, a3=0.f;
    const uint4* hv = (const uint4*)h_lds;
    #pragma unroll
    for (int i = 0; i < 32; ++i){
      uint4 h4 = hv[i];
      uint4 wi = w[i];
      a0 = dot2f(wi.x, bc2(h4.x), a0);
      a1 = dot2f(wi.y, bc2(h4.y), a1);
      a2 = dot2f(wi.z, bc2(h4.z), a2);
      a3 = dot2f(wi.w, bc2(h4.w), a3);
    }
    gh[j] = (a0+a1)+(a2+a3);
    __syncthreads();
    if (j < HE){
      float gr = wv0[j]*x0 + wv1[j]*x1 + bis[j] + gh[j] + bhs[j];
      float gz = wv0[j+HE]*x0 + wv1[j+HE]*x1 + bis[j+HE] + gh[j+HE] + bhs[j+HE];
      float r = sigm(gr), z = sigm(gz);
      float gin = wv0[j+2*HE]*x0 + wv1[j+2*HE]*x1 + bis[j+2*HE];
      float n = ftanh(gin + r*(gh[j+2*HE] + bhs[j+2*HE]));
      float hnew = (1.f - z)*n + z*h_own;
      h_own = hnew;
      h_lds[j] = (f16)hnew;
      enc_out[((size_t)b*TT + tt)*HD + dir*HE + j] = f2bf(hnew);
    }
    __syncthreads();
  }
  if (j < HE) h0out[(size_t)b*HD + dir*HE + j] = h_own;
}

// ---------- decoder: ONE STEP per launch, M-parallel ----------
// grid 256 = (bg 4) x (cg 64); block 256 thr. Block: 32 batches x 8 cols.
// thread (ci=tid&7, kq=(tid>>3)&7, bq=tid>>6): weights {ci,+512,+1024} rows,
// k-seg [kq*64,+64) in 24 uint4 REGs (coalesced); 8 batches' partial dots;
// LDS reduce over kq; gates fused. Weight traffic/step = 4 x 1.5 MB only.
__global__ __launch_bounds__(256, 2) void k_dstep(
    const int* __restrict__ tgt, const float* __restrict__ gi_tab,
    const uint4* __restrict__ Wd2, const float* __restrict__ bhh,
    const f16* __restrict__ h_prev, f16* __restrict__ h_next,
    float* __restrict__ Hall, int l)
{
  const int bg = blockIdx.x & 3, cg = blockIdx.x >> 2;
  const int tid = threadIdx.x;
  const int ci = tid & 7, kq = (tid >> 3) & 7, bq = tid >> 6;

  __shared__ __align__(16) f16 h_s[32][HD];       // 32 KB
  __shared__ float p_s[3][32][8][8];              // 24 KB [g][b][ci][kq]
  __shared__ int tok_s[32];

  // weights -> 24 uint4 regs (lane-coalesced layout)
  uint4 w[24];
  {
    const uint4* wp = Wd2 + (size_t)cg*24*64 + (kq*8 + ci);
    #pragma unroll
    for (int i = 0; i < 24; ++i) w[i] = wp[(size_t)i*64];
  }
  // stage h tile (32 batches x 512 f16 = 2048 uint4)
  {
    const uint4* hsrc = (const uint4*)(h_prev + (size_t)bg*32*HD);
    uint4* hdst = (uint4*)&h_s[0][0];
    #pragma unroll
    for (int i = 0; i < 8; ++i) hdst[tid + i*256] = hsrc[tid + i*256];
  }
  if (tid < 32) tok_s[tid] = (l == 0) ? 1 : tgt[(size_t)(bg*32 + tid)*LL + l - 1];
  __syncthreads();

  // partial dots: 8 batches x 3 gates over this thread's 64-wide k-segment
  #pragma unroll
  for (int nb = 0; nb < 8; ++nb){
    const int b = bq*8 + nb;
    const uint4* hv = (const uint4*)&h_s[b][kq*64];
    float x0 = 0.f, x1 = 0.f, x2 = 0.f;
    #pragma unroll
    for (int u = 0; u < 8; ++u){
      uint4 hh = hv[u];
      dot_u4(w[u],      hh, x0);
      dot_u4(w[8 + u],  hh, x1);
      dot_u4(w[16 + u], hh, x2);
    }
    p_s[0][b][ci][kq] = x0;
    p_s[1][b][ci][kq] = x1;
    p_s[2][b][ci][kq] = x2;
  }
  __syncthreads();

  // reduce over kq + gates: thread = (b=tid>>3, cl=tid&7)
  {
    const int b = tid >> 3, cl = tid & 7;
    const int C = cg*8 + cl;
    float s0 = 0.f, s1 = 0.f, s2 = 0.f;
    #pragma unroll
    for (int k = 0; k < 8; ++k){
      s0 += p_s[0][b][cl][k];
      s1 += p_s[1][b][cl][k];
      s2 += p_s[2][b][cl][k];
    }
    const int tok = tok_s[b];
    const float* gp = gi_tab + (size_t)tok*G3D + C;
    float r = sigm(gp[0]    + s0 + bhh[C]);
    float z = sigm(gp[HD]   + s1 + bhh[HD + C]);
    float n = ftanh(gp[2*HD] + r*(s2 + bhh[2*HD + C]));
    float hp = (float)h_s[b][C];
    float hnew = (1.f - z)*n + z*hp;
    const int gb = bg*32 + b;
    h_next[(size_t)gb*HD + C] = (f16)hnew;
    Hall[((size_t)l*BB + gb)*HD + C] = hnew;
  }
}

// ---------- Q = Hall @ WqT + bq -> bf16 ; grid (128 rt, 8 nt) ----------
__global__ __launch_bounds__(256) void k_query(const float* __restrict__ Hall,
                                               const float* __restrict__ WqT,
                                               const float* __restrict__ bq,
                                               u16* __restrict__ Qbf){
  const int rt = blockIdx.x, nt = blockIdx.y;
  const int tid = threadIdx.x;
  __shared__ float A_s[32*68];
  __shared__ float B_s[32*68];
  const int rq = tid >> 4, nq = tid & 15;
  const int i = tid >> 2, jj = tid & 3;
  const int i2 = tid >> 3, jj2 = tid & 7;
  float acc[16] = {};
  for (int kc = 0; kc < 16; ++kc){
    __syncthreads();
    {
      const float* src = Hall + (size_t)(rt*64 + i)*HD + kc*32 + jj*8;
      float4 v0 = *(const float4*)src, v1 = *(const float4*)(src+4);
      A_s[(jj*8+0)*68+i]=v0.x; A_s[(jj*8+1)*68+i]=v0.y;
      A_s[(jj*8+2)*68+i]=v0.z; A_s[(jj*8+3)*68+i]=v0.w;
      A_s[(jj*8+4)*68+i]=v1.x; A_s[(jj*8+5)*68+i]=v1.y;
      A_s[(jj*8+6)*68+i]=v1.z; A_s[(jj*8+7)*68+i]=v1.w;
    }
    {
      const float* src = WqT + (size_t)(kc*32 + i2)*HD + nt*64 + jj2*8;
      *(float4*)&B_s[i2*68 + jj2*8]     = *(const float4*)src;
      *(float4*)&B_s[i2*68 + jj2*8 + 4] = *(const float4*)(src+4);
    }
    __syncthreads();
    INNER16(rq, nq)
  }
  const int n0 = nt*64 + nq*4;
  float4 bv = *(const float4*)&bq[n0];
  #pragma unroll
  for (int r = 0; r < 4; ++r){
    u16* dst = Qbf + (size_t)(rt*64 + rq*4 + r)*HD + n0;
    *(ushort4*)dst = pk4(acc[r*4+0]+bv.x, acc[r*4+1]+bv.y,
                         acc[r*4+2]+bv.z, acc[r*4+3]+bv.w);
  }
}

// ---------- S[b][l][t] = Q[b,l,:] . enc[b,t,:] ; grid (128 b, 8 tt) ----------
__global__ __launch_bounds__(256) void k_scores(const u16* __restrict__ Qbf,
                                                const u16* __restrict__ enc,
                                                float* __restrict__ Sbuf){
  const int bI = blockIdx.x, tt = blockIdx.y;
  const int tid = threadIdx.x;
  __shared__ float A_s[32*68];
  __shared__ float B_s[32*68];
  const int lq = tid >> 4, tq = tid & 15;
  const int i = tid >> 2, jj = tid & 3;
  float acc[16] = {};
  for (int kc = 0; kc < 16; ++kc){
    __syncthreads();
    float tmp[8];
    {
      uint4 va = *(const uint4*)(Qbf + ((size_t)i*BB + bI)*HD + kc*32 + jj*8);
      unp8(va, tmp);
      #pragma unroll
      for (int m = 0; m < 8; ++m) A_s[(jj*8+m)*68 + i] = tmp[m];
    }
    {
      uint4 vb = *(const uint4*)(enc + ((size_t)bI*TT + tt*64 + i)*HD + kc*32 + jj*8);
      unp8(vb, tmp);
      #pragma unroll
      for (int m = 0; m < 8; ++m) B_s[(jj*8+m)*68 + i] = tmp[m];
    }
    __syncthreads();
    INNER16(lq, tq)
  }
  #pragma unroll
  for (int r = 0; r < 4; ++r){
    float4 o = make_float4(acc[r*4+0],acc[r*4+1],acc[r*4+2],acc[r*4+3]);
    *(float4*)&Sbuf[((size_t)bI*LL + lq*4+r)*TT + tt*64 + tq*4] = o;
  }
}

// ---------- row softmax over t: P bf16 ; grid 8192 x 64 ----------
__global__ __launch_bounds__(64) void k_softmax(const float* __restrict__ Sbuf,
                                                u16* __restrict__ Pbf){
  const int row = blockIdx.x;
  const int lane = threadIdx.x;
  const float* s = Sbuf + (size_t)row*TT;
  float v[8]; float m = -1e30f;
  #pragma unroll
  for (int i = 0; i < 8; ++i){ v[i] = s[lane + i*64]; m = fmaxf(m, v[i]); }
  #pragma unroll
  for (int o = 32; o; o >>= 1) m = fmaxf(m, __shfl_xor(m, o));
  float Z = 0.f;
  #pragma unroll
  for (int i = 0; i < 8; ++i){ v[i] = fexp2(1.4426950408889634f*(v[i] - m)); Z += v[i]; }
  #pragma unroll
  for (int o = 32; o; o >>= 1) Z += __shfl_xor(Z, o);
  float inv = frcp(Z);
  u16* p = Pbf + (size_t)row*TT;
  #pragma unroll
  for (int i = 0; i < 8; ++i) p[lane + i*64] = f2bf(v[i]*inv);
}

// ---------- attn[b][t][l] = f32(P[b][l][t]) ; grid (128 b, 8 tt) ----------
__global__ __launch_bounds__(256) void k_attn_tr(const u16* __restrict__ Pbf,
                                                 float* __restrict__ att){
  const int bI = blockIdx.x, tt = blockIdx.y;
  const int tid = threadIdx.x;
  __shared__ u16 tile[64][72];
  {
    const int i = tid >> 2, jj = tid & 3;
    #pragma unroll
    for (int rep = 0; rep < 2; ++rep){
      int ch = jj + rep*4;
      uint4 v = *(const uint4*)(Pbf + ((size_t)bI*LL + i)*TT + tt*64 + ch*8);
      *(uint4*)&tile[i][ch*8] = v;
    }
  }
  __syncthreads();
  const int t = tid >> 2, jl = tid & 3;
  #pragma unroll
  for (int rep = 0; rep < 4; ++rep){
    int l0 = jl*16 + rep*4;
    float4 o;
    o.x = bf2f(tile[l0+0][t]); o.y = bf2f(tile[l0+1][t]);
    o.z = bf2f(tile[l0+2][t]); o.w = bf2f(tile[l0+3][t]);
    *(float4*)&att[((size_t)bI*TT + tt*64 + t)*LL + l0] = o;
  }
}

// ---------- ctx[l*128+b][n] = P[b,l,:] @ enc[b,:,n] -> bf16 ; grid (128 b, 8 nt) ----------
__global__ __launch_bounds__(256) void k_ctx(const u16* __restrict__ Pbf,
                                             const u16* __restrict__ enc,
                                             u16* __restrict__ ctxb){
  const int bI = blockIdx.x, nt = blockIdx.y;
  const int tid = threadIdx.x;
  __shared__ float A_s[32*68];
  __shared__ float B_s[32*68];
  const int lq = tid >> 4, nq = tid & 15;
  const int i = tid >> 2, jj = tid & 3;
  const int i2 = tid >> 3, jj2 = tid & 7;
  float acc[16] = {};
  for (int tc = 0; tc < 16; ++tc){
    __syncthreads();
    {
      float tmp[8];
      uint4 va = *(const uint4*)(Pbf + ((size_t)bI*LL + i)*TT + tc*32 + jj*8);
      unp8(va, tmp);
      #pragma unroll
      for (int m = 0; m < 8; ++m) A_s[(jj*8+m)*68 + i] = tmp[m];
    }
    {
      float tmp[8];
      uint4 vb = *(const uint4*)(enc + ((size_t)bI*TT + tc*32 + i2)*HD + nt*64 + jj2*8);
      unp8(vb, tmp);
      *(float4*)&B_s[i2*68 + jj2*8]     = make_float4(tmp[0],tmp[1],tmp[2],tmp[3]);
      *(float4*)&B_s[i2*68 + jj2*8 + 4] = make_float4(tmp[4],tmp[5],tmp[6],tmp[7]);
    }
    __syncthreads();
    INNER16(lq, nq)
  }
  const int n0 = nt*64 + nq*4;
  #pragma unroll
  for (int r = 0; r < 4; ++r){
    int ll = lq*4 + r;
    u16* dst = ctxb + ((size_t)ll*BB + bI)*HD + n0;
    *(ushort4*)dst = pk4(acc[r*4+0], acc[r*4+1], acc[r*4+2], acc[r*4+3]);
  }
}

// ---------- o = [Hall|ctx] @ WcT + bc ; grid (128 rt, 4 nt) ----------
__global__ __launch_bounds__(256) void k_outc(const float* __restrict__ Hall,
                                              const u16* __restrict__ ctxb,
                                              const float* __restrict__ WcT,
                                              const float* __restrict__ bc,
                                              float* __restrict__ obuf){
  const int rt = blockIdx.x, nt = blockIdx.y;
  const int tid = threadIdx.x;
  __shared__ float A_s[32*68];
  __shared__ float B_s[32*68];
  const int rq = tid >> 4, nq = tid & 15;
  const int i = tid >> 2, jj = tid & 3;
  const int i2 = tid >> 3, jj2 = tid & 7;
  float acc[16] = {};
  for (int kc = 0; kc < 32; ++kc){
    __syncthreads();
    if (kc < 16){
      const float* src = Hall + (size_t)(rt*64 + i)*HD + kc*32 + jj*8;
      float4 v0 = *(const float4*)src, v1 = *(const float4*)(src+4);
      A_s[(jj*8+0)*68+i]=v0.x; A_s[(jj*8+1)*68+i]=v0.y;
      A_s[(jj*8+2)*68+i]=v0.z; A_s[(jj*8+3)*68+i]=v0.w;
      A_s[(jj*8+4)*68+i]=v1.x; A_s[(jj*8+5)*68+i]=v1.y;
      A_s[(jj*8+6)*68+i]=v1.z; A_s[(jj*8+7)*68+i]=v1.w;
    } else {
      float tmp[8];
      uint4 v = *(const uint4*)(ctxb + (size_t)(rt*64 + i)*HD + (kc-16)*32 + jj*8);
      unp8(v, tmp);
      #pragma unroll
      for (int m = 0; m < 8; ++m) A_s[(jj*8+m)*68 + i] = tmp[m];
    }
    {
      const float* src = WcT + (size_t)(kc*32 + i2)*256 + nt*64 + jj2*8;
      *(float4*)&B_s[i2*68 + jj2*8]     = *(const float4*)src;
      *(float4*)&B_s[i2*68 + jj2*8 + 4] = *(const float4*)(src+4);
    }
    __syncthreads();
    INNER16(rq, nq)
  }
  const int n0 = nt*64 + nq*4;
  float4 bv = *(const float4*)&bc[n0];
  #pragma unroll
  for (int r = 0; r < 4; ++r){
    float4 o = make_float4(acc[r*4+0]+bv.x, acc[r*4+1]+bv.y,
                           acc[r*4+2]+bv.z, acc[r*4+3]+bv.w);
    *(float4*)&obuf[(size_t)(rt*64 + rq*4 + r)*256 + n0] = o;
  }
}

// ---------- logits = o @ Wf^T + bf ; grid 128 ----------
__global__ __launch_bounds__(256) void k_fc(const float* __restrict__ obuf,
                                            const float* __restrict__ Wf,
                                            const float* __restrict__ bfv,
                                            float* __restrict__ out_vec){
  const int rt = blockIdx.x;
  const int tid = threadIdx.x;
  __shared__ float w_s[30*260];
  for (int rr = 0; rr < 30; ++rr) w_s[rr*260 + tid] = Wf[(size_t)rr*256 + tid];
  __syncthreads();
  const int rl = tid >> 2, dq = tid & 3;
  const int r = rt*64 + rl;
  float acc[8] = {};
  for (int k = 0; k < 256; k += 4){
    float4 o4 = *(const float4*)&obuf[(size_t)r*256 + k];
    #pragma unroll
    for (int jq = 0; jq < 8; ++jq){
      int d = dq*8 + jq;
      if (d < 30){
        float4 w4 = *(const float4*)&w_s[d*260 + k];
        acc[jq] = fmaf(o4.x,w4.x,fmaf(o4.y,w4.y,fmaf(o4.z,w4.z,fmaf(o4.w,w4.w,acc[jq]))));
      }
    }
  }
  const int b = r & 127, l = r >> 7;
  #pragma unroll
  for (int jq = 0; jq < 8; ++jq){
    int d = dq*8 + jq;
    if (d < 30) out_vec[((size_t)b*LL + l)*NDICT + d] = acc[jq] + bfv[d];
  }
}

__global__ __launch_bounds__(256) void k_copy(const float* __restrict__ src,
                                              float* __restrict__ dst, int n){
  int i = blockIdx.x*256 + threadIdx.x;
  if (i < n) dst[i] = src[i];
}

extern "C" void kernel_launch(void* const* d_in, const int* in_sizes, int n_in,
                              void* d_out, int out_size, void* d_ws, size_t ws_size,
                              hipStream_t stream)
{
  const float* x     = (const float*)d_in[0];
  const int*   tgt   = (const int*)  d_in[1];
  const float* eWihF = (const float*)d_in[2];
  const float* eWhhF = (const float*)d_in[3];
  const float* ebihF = (const float*)d_in[4];
  const float* ebhhF = (const float*)d_in[5];
  const float* eWihB = (const float*)d_in[6];
  const float* eWhhB = (const float*)d_in[7];
  const float* ebihB = (const float*)d_in[8];
  const float* ebhhB = (const float*)d_in[9];
  const float* emb   = (const float*)d_in[10];
  const float* dWih  = (const float*)d_in[11];
  const float* dWhh  = (const float*)d_in[12];
  const float* dbih  = (const float*)d_in[13];
  const float* dbhh  = (const float*)d_in[14];
  const float* Wq    = (const float*)d_in[15];
  const float* bq    = (const float*)d_in[16];
  const float* Wc    = (const float*)d_in[17];
  const float* bc    = (const float*)d_in[18];
  const float* Wf    = (const float*)d_in[19];
  const float* bfv   = (const float*)d_in[20];

  char* w = (char*)d_ws;
  uint4* Wpenc = (uint4*)w; w += 786432;     // [2][32][768] uint4 f16
  uint4* Wpdec = (uint4*)w; w += 1572864;    // [64][24][64] uint4 f16 M-parallel
  float* WqT   = (float*)w; w += 1048576;
  float* WcT   = (float*)w; w += 1048576;
  float* gi_t  = (float*)w; w += 184320;
  float* h0buf = (float*)w; w += 262144;
  f16*   h16A  = (f16*)w; w += 131072;       // [128][512] f16
  f16*   h16B  = (f16*)w; w += 131072;
  float* Hall  = (float*)w; w += 16777216;
  u16*   Qbf   = (u16*)w;                    // aliased: Pbf reuses after k_scores
  u16*   Pbf   = (u16*)w; w += 8388608;
  float* Sbuf  = (float*)w;                  // aliased over (ctxb | obuf)
  u16*   ctxb  = (u16*)w; w += 8388608;
  float* obuf  = (float*)w; w += 8388608;
  u16*   encb  = (u16*)w; w += 67108864;

  float* out     = (float*)d_out;
  float* out_vec = out;                              // [128][64][30]
  float* out_hT  = out + (size_t)BB*LL*NDICT;        // [1][128][512]
  float* out_att = out_hT + (size_t)BB*HD;           // [128][512][64]

  // prep
  k_prep_wenc<<<192, 256, 0, stream>>>(eWhhF, eWhhB, Wpenc);
  k_prep_wdec<<<384, 256, 0, stream>>>(dWhh, Wpdec);
  k_transpose<<<(HD*HD+255)/256, 256, 0, stream>>>(Wq, WqT, HD, HD);
  k_transpose<<<(256*1024+255)/256, 256, 0, stream>>>(Wc, WcT, 256, 1024);
  k_gi_tab<<<dim3(NDICT, 6), 256, 0, stream>>>(emb, dWih, dbih, gi_t);

  // encoder: 256 independent recurrences, weights register-resident
  k_enc_p<<<BB*2, G3E, 0, stream>>>(x, Wpenc, eWihF, eWihB,
                                    ebihF, ebhhF, ebihB, ebhhB, encb, h0buf);

  // decoder recurrence: one launch per step, M-parallel (weights 4x1.5MB/step)
  k_h0cvt<<<256, 256, 0, stream>>>(h0buf, h16A);
  for (int l = 0; l < LL; ++l){
    const f16* hp = (l & 1) ? h16B : h16A;
    f16*       hn = (l & 1) ? h16A : h16B;
    k_dstep<<<256, 256, 0, stream>>>(tgt, gi_t, Wpdec, dbhh, hp, hn, Hall, l);
  }

  // batched post-recurrence pipeline
  k_query<<<dim3(128,8), 256, 0, stream>>>(Hall, WqT, bq, Qbf);
  k_scores<<<dim3(128,8), 256, 0, stream>>>(Qbf, encb, Sbuf);
  k_softmax<<<BB*LL, 64, 0, stream>>>(Sbuf, Pbf);
  k_attn_tr<<<dim3(128,8), 256, 0, stream>>>(Pbf, out_att);
  k_ctx<<<dim3(128,8), 256, 0, stream>>>(Pbf, encb, ctxb);
  k_outc<<<dim3(128,4), 256, 0, stream>>>(Hall, ctxb, WcT, bc, obuf);
  k_fc<<<BB, 256, 0, stream>>>(obuf, Wf, bfv, out_vec);
  k_copy<<<(BB*HD+255)/256, 256, 0, stream>>>(Hall + (size_t)63*BB*HD, out_hT, BB*HD);
}

// Round 9
// 1221.893 us; speedup vs baseline: 3.2372x; 1.0863x over previous
//
#include <hip/hip_runtime.h>
#include <hip/hip_bf16.h>

typedef unsigned int u32;
typedef unsigned short u16;
typedef _Float16 f16;
typedef f16 f16x2 __attribute__((ext_vector_type(2)));

#define BB 128
#define TT 512
#define HE 256      // encoder hidden
#define G3E 768
#define HD 512      // decoder hidden (2H)
#define G3D 1536
#define LL 64
#define NDICT 30
#define EMBD 256

__device__ __forceinline__ float fexp2(float v){
#if __has_builtin(__builtin_amdgcn_exp2f)
  return __builtin_amdgcn_exp2f(v);
#else
  return exp2f(v);
#endif
}
__device__ __forceinline__ float frcp(float v){
#if __has_builtin(__builtin_amdgcn_rcpf)
  return __builtin_amdgcn_rcpf(v);
#else
  return 1.f/v;
#endif
}
__device__ __forceinline__ float sigm(float v){
  return frcp(1.f + fexp2(-1.4426950408889634f*v));
}
__device__ __forceinline__ float ftanh(float v){
  float e = fexp2(fminf(v, 40.f)*2.8853901631790583f);
  return (e - 1.f)*frcp(e + 1.f);
}
__device__ __forceinline__ u16 f2h(float f){ return __builtin_bit_cast(u16, (f16)f); }
__device__ __forceinline__ float h2f(u16 b){ return (float)__builtin_bit_cast(f16, b); }
__device__ __forceinline__ u32 pkh2(float a, float b){
  u16 lo = __builtin_bit_cast(u16, (f16)a);
  u16 hi = __builtin_bit_cast(u16, (f16)b);
  return (u32)lo | ((u32)hi << 16);
}
__device__ __forceinline__ u32 pkrtz(float a, float b){
  return __builtin_bit_cast(u32, __builtin_amdgcn_cvt_pkrtz(a, b));
}
__device__ __forceinline__ f16x2 bc2(u32 v){ return __builtin_bit_cast(f16x2, v); }

__device__ __forceinline__ void unp8h(uint4 v, float* d){
  f16x2 p;
  p = bc2(v.x); d[0]=(float)p.x; d[1]=(float)p.y;
  p = bc2(v.y); d[2]=(float)p.x; d[3]=(float)p.y;
  p = bc2(v.z); d[4]=(float)p.x; d[5]=(float)p.y;
  p = bc2(v.w); d[6]=(float)p.x; d[7]=(float)p.y;
}
__device__ __forceinline__ ushort4 hpk4(float a, float b, float c, float d){
  ushort4 r; r.x=f2h(a); r.y=f2h(b); r.z=f2h(c); r.w=f2h(d); return r;
}

// dot2: acc += a(2xf16) . b(2xf16), f32 accumulate
__device__ __forceinline__ float dot2f(u32 w, f16x2 h, float acc){
#if __has_builtin(__builtin_amdgcn_fdot2)
  return __builtin_amdgcn_fdot2(__builtin_bit_cast(f16x2, w), h, acc, false);
#else
  f16x2 wv = __builtin_bit_cast(f16x2, w);
  acc = fmaf((float)wv.x, (float)h.x, acc);
  return fmaf((float)wv.y, (float)h.y, acc);
#endif
}
__device__ __forceinline__ float dot2h(u32 a, u32 b, float acc){
  return dot2f(a, bc2(b), acc);
}
__device__ __forceinline__ void dot_u4(uint4 wv, uint4 hv, float& acc){
  acc = dot2f(wv.x, bc2(hv.x), acc);
  acc = dot2f(wv.y, bc2(hv.y), acc);
  acc = dot2f(wv.z, bc2(hv.z), acc);
  acc = dot2f(wv.w, bc2(hv.w), acc);
}

// f32 16-FMA inner (A_s/B_s [32][68] f32 k-major) — used by k_ctx
#define INNER16(Q0,Q1)                                              \
  _Pragma("unroll 8")                                               \
  for (int k = 0; k < 32; ++k){                                     \
    float4 a4 = *(const float4*)&A_s[k*68 + (Q0)*4];                \
    float4 b4 = *(const float4*)&B_s[k*68 + (Q1)*4];                \
    acc[0] =fmaf(a4.x,b4.x,acc[0]);  acc[1] =fmaf(a4.x,b4.y,acc[1]); \
    acc[2] =fmaf(a4.x,b4.z,acc[2]);  acc[3] =fmaf(a4.x,b4.w,acc[3]); \
    acc[4] =fmaf(a4.y,b4.x,acc[4]);  acc[5] =fmaf(a4.y,b4.y,acc[5]); \
    acc[6] =fmaf(a4.y,b4.z,acc[6]);  acc[7] =fmaf(a4.y,b4.w,acc[7]); \
    acc[8] =fmaf(a4.z,b4.x,acc[8]);  acc[9] =fmaf(a4.z,b4.y,acc[9]); \
    acc[10]=fmaf(a4.z,b4.z,acc[10]); acc[11]=fmaf(a4.z,b4.w,acc[11]);\
    acc[12]=fmaf(a4.w,b4.x,acc[12]); acc[13]=fmaf(a4.w,b4.y,acc[13]);\
    acc[14]=fmaf(a4.w,b4.z,acc[14]); acc[15]=fmaf(a4.w,b4.w,acc[15]);\
  }

// f16-pair dot2 inner (A2_s/B2_s u32[16][68], each u32 = 2 consecutive k)
#define INNER8P(Q0,Q1)                                                  \
  _Pragma("unroll")                                                     \
  for (int kp = 0; kp < 16; ++kp){                                      \
    uint4 a2 = *(const uint4*)&A2_s[kp*68 + (Q0)*4];                    \
    uint4 b2 = *(const uint4*)&B2_s[kp*68 + (Q1)*4];                    \
    acc[0] =dot2h(a2.x,b2.x,acc[0]);  acc[1] =dot2h(a2.x,b2.y,acc[1]);  \
    acc[2] =dot2h(a2.x,b2.z,acc[2]);  acc[3] =dot2h(a2.x,b2.w,acc[3]);  \
    acc[4] =dot2h(a2.y,b2.x,acc[4]);  acc[5] =dot2h(a2.y,b2.y,acc[5]);  \
    acc[6] =dot2h(a2.y,b2.z,acc[6]);  acc[7] =dot2h(a2.y,b2.w,acc[7]);  \
    acc[8] =dot2h(a2.z,b2.x,acc[8]);  acc[9] =dot2h(a2.z,b2.y,acc[9]);  \
    acc[10]=dot2h(a2.z,b2.z,acc[10]); acc[11]=dot2h(a2.z,b2.w,acc[11]); \
    acc[12]=dot2h(a2.w,b2.x,acc[12]); acc[13]=dot2h(a2.w,b2.y,acc[13]); \
    acc[14]=dot2h(a2.w,b2.z,acc[14]); acc[15]=dot2h(a2.w,b2.w,acc[15]); \
  }

// ---------- prep: pair-transposed f16 weights  dst[kp*N+n] = pack(src[n][2kp],src[n][2kp+1])
__global__ __launch_bounds__(256) void k_prep_pairT(const float* __restrict__ src,
                                                    u32* __restrict__ dst, int N, int K){
  int idx = blockIdx.x*256 + threadIdx.x;
  int KP = K >> 1;
  if (idx < N*KP){
    int n = idx / KP, kp = idx - n*KP;
    dst[(size_t)kp*N + n] = pkh2(src[(size_t)n*K + 2*kp], src[(size_t)n*K + 2*kp + 1]);
  }
}

// ---------- prep: encoder Whh -> f16 chunk-major [dir][i 32][j 768] uint4 ----------
__global__ __launch_bounds__(256) void k_prep_wenc(const float* __restrict__ WF,
                                                   const float* __restrict__ WB,
                                                   uint4* __restrict__ dst){
  int idx = blockIdx.x*256 + threadIdx.x;   // 49152 = 2*32*768
  int dir = idx / 24576, rem = idx - dir*24576;
  int i = rem / 768, j = rem - i*768;
  const float* s = (dir ? WB : WF) + (size_t)j*HE + i*8;
  uint4 v; v.x=pkh2(s[0],s[1]); v.y=pkh2(s[2],s[3]); v.z=pkh2(s[4],s[5]); v.w=pkh2(s[6],s[7]);
  dst[idx] = v;
}

// ---------- prep: decoder Whh -> f16 M-parallel layout ----------
__global__ __launch_bounds__(256) void k_prep_wdec(const float* __restrict__ src,
                                                   uint4* __restrict__ dst){
  int idx = blockIdx.x*256 + threadIdx.x;   // 98304 = 64*24*64
  int lane = idx & 63;
  int ci = lane & 7, kq = lane >> 3;
  int rest = idx >> 6;                      // cg*24 + g*8 + u
  int u = rest & 7, g = (rest >> 3) % 3, cg = rest / 24;
  int row = g*512 + cg*8 + ci;
  int col = kq*64 + u*8;
  const float* s = src + (size_t)row*HD + col;
  uint4 v; v.x=pkh2(s[0],s[1]); v.y=pkh2(s[2],s[3]); v.z=pkh2(s[4],s[5]); v.w=pkh2(s[6],s[7]);
  dst[idx] = v;
}

// ---------- prep: gi[v][g] = emb[v]@dWih[g] + bih[g] ----------
__global__ __launch_bounds__(256) void k_gi_tab(const float* __restrict__ emb,
                                                const float* __restrict__ Wih,
                                                const float* __restrict__ bih,
                                                float* __restrict__ gi){
  int v = blockIdx.x, gy = blockIdx.y;   // grid (30, 6)
  int g = gy*256 + threadIdx.x;
  __shared__ float e_s[EMBD];
  if (threadIdx.x < EMBD) e_s[threadIdx.x] = emb[(size_t)v*EMBD + threadIdx.x];
  __syncthreads();
  const float4* w4 = (const float4*)(Wih + (size_t)g*EMBD);
  float acc = 0.f;
  #pragma unroll 8
  for (int k = 0; k < EMBD/4; ++k){
    float4 w = w4[k];
    float4 h = *(const float4*)&e_s[k*4];
    acc = fmaf(w.x,h.x,fmaf(w.y,h.y,fmaf(w.z,h.z,fmaf(w.w,h.w,acc))));
  }
  gi[(size_t)v*G3D + g] = acc + bih[g];
}

// ---------- prep: h0 f32 -> f16 ----------
__global__ __launch_bounds__(256) void k_h0cvt(const float* __restrict__ src,
                                               f16* __restrict__ dst){
  int i = blockIdx.x*256 + threadIdx.x;   // 65536
  dst[i] = (f16)src[i];
}

// ---------- encoder: one block per (batch, direction); weights in VGPRs ----------
// Folded gates: dot threads write FINISHED pre-activations; gates phase is
// 4 LDS reads + 2 sigm + 1 tanh. Per-thread Wih/bias in registers (no LDS).
__global__ __launch_bounds__(768, 3) void k_enc_p(
    const float* __restrict__ x,
    const uint4* __restrict__ Wp,               // [2][32][768] uint4, chunk-major
    const float* __restrict__ WihF, const float* __restrict__ WihB,
    const float* __restrict__ bihF, const float* __restrict__ bhhF,
    const float* __restrict__ bihB, const float* __restrict__ bhhB,
    u16* __restrict__ enc_out, float* __restrict__ h0out)
{
  const int b   = blockIdx.x >> 1;
  const int dir = blockIdx.x & 1;
  const int j   = threadIdx.x;
  const float* Wih = dir ? WihB : WihF;
  const float* bih = dir ? bihB : bihF;
  const float* bhh = dir ? bhhB : bhhF;

  __shared__ __align__(16) f16 h_lds[HE];   // 512 B
  __shared__ float gh[2*HE];                // 2 KB: finished r,z pre-acts
  __shared__ float gin_s[HE], ghn_s[HE];    // 2 KB: n-gate halves

  // Whh row j -> 32 uint4 (128 VGPRs), coalesced chunk-major load
  uint4 w[32];
  {
    const uint4* wsrc = Wp + (size_t)dir*24576 + j;
    #pragma unroll
    for (int i = 0; i < 32; ++i) w[i] = wsrc[(size_t)i*768];
  }
  const float wv0r = Wih[j*2+0], wv1r = Wih[j*2+1];
  const float bi = bih[j], bh = bhh[j];
  const float badd = bi + bh;               // for r,z rows
  if (j < HE) h_lds[j] = (f16)0.f;
  float h_own = 0.f;
  __syncthreads();

  for (int t = 0; t < TT; ++t){
    const int tt = dir ? (TT-1-t) : t;
    const float x0 = x[((size_t)b*TT + tt)*2 + 0];
    const float x1 = x[((size_t)b*TT + tt)*2 + 1];

    float a0=0.f, a1=0.f, a2=0.f, a3=0.f;
    const uint4* hv = (const uint4*)h_lds;
    #pragma unroll
    for (int i = 0; i < 32; ++i){
      uint4 h4 = hv[i];
      uint4 wi = w[i];
      a0 = dot2f(wi.x, bc2(h4.x), a0);
      a1 = dot2f(wi.y, bc2(h4.y), a1);
      a2 = dot2f(wi.z, bc2(h4.z), a2);
      a3 = dot2f(wi.w, bc2(h4.w), a3);
    }
    const float acc = (a0+a1)+(a2+a3);
    const float xp = fmaf(wv0r, x0, wv1r*x1);
    if (j < 2*HE){
      gh[j] = acc + xp + badd;              // r,z: fully folded
    } else {
      ghn_s[j-2*HE] = acc + bh;
      gin_s[j-2*HE] = xp + bi;
    }
    __syncthreads();
    if (j < HE){
      float r = sigm(gh[j]);
      float z = sigm(gh[j+HE]);
      float n = ftanh(gin_s[j] + r*ghn_s[j]);
      float hnew = (1.f - z)*n + z*h_own;
      h_own = hnew;
      h_lds[j] = (f16)hnew;
      enc_out[((size_t)b*TT + tt)*HD + dir*HE + j] = f2h(hnew);
    }
    __syncthreads();
  }
  if (j < HE) h0out[(size_t)b*HD + dir*HE + j] = h_own;
}

// ---------- decoder: ONE STEP per launch, M-parallel ----------
__global__ __launch_bounds__(256, 2) void k_dstep(
    const int* __restrict__ tgt, const float* __restrict__ gi_tab,
    const uint4* __restrict__ Wd2, const float* __restrict__ bhh,
    const f16* __restrict__ h_prev, f16* __restrict__ h_next,
    float* __restrict__ Hall, int l)
{
  const int bg = blockIdx.x & 3, cg = blockIdx.x >> 2;
  const int tid = threadIdx.x;
  const int ci = tid & 7, kq = (tid >> 3) & 7, bq = tid >> 6;

  __shared__ __align__(16) f16 h_s[32][HD];       // 32 KB
  __shared__ float p_s[3][32][8][8];              // 24 KB [g][b][ci][kq]
  __shared__ int tok_s[32];

  uint4 w[24];
  {
    const uint4* wp = Wd2 + (size_t)cg*24*64 + (kq*8 + ci);
    #pragma unroll
    for (int i = 0; i < 24; ++i) w[i] = wp[(size_t)i*64];
  }
  {
    const uint4* hsrc = (const uint4*)(h_prev + (size_t)bg*32*HD);
    uint4* hdst = (uint4*)&h_s[0][0];
    #pragma unroll
    for (int i = 0; i < 8; ++i) hdst[tid + i*256] = hsrc[tid + i*256];
  }
  if (tid < 32) tok_s[tid] = (l == 0) ? 1 : tgt[(size_t)(bg*32 + tid)*LL + l - 1];
  __syncthreads();

  #pragma unroll
  for (int nb = 0; nb < 8; ++nb){
    const int b = bq*8 + nb;
    const uint4* hv = (const uint4*)&h_s[b][kq*64];
    float x0 = 0.f, x1 = 0.f, x2 = 0.f;
    #pragma unroll
    for (int u = 0; u < 8; ++u){
      uint4 hh = hv[u];
      dot_u4(w[u],      hh, x0);
      dot_u4(w[8 + u],  hh, x1);
      dot_u4(w[16 + u], hh, x2);
    }
    p_s[0][b][ci][kq] = x0;
    p_s[1][b][ci][kq] = x1;
    p_s[2][b][ci][kq] = x2;
  }
  __syncthreads();

  {
    const int b = tid >> 3, cl = tid & 7;
    const int C = cg*8 + cl;
    float s0 = 0.f, s1 = 0.f, s2 = 0.f;
    #pragma unroll
    for (int k = 0; k < 8; ++k){
      s0 += p_s[0][b][cl][k];
      s1 += p_s[1][b][cl][k];
      s2 += p_s[2][b][cl][k];
    }
    const int tok = tok_s[b];
    const float* gp = gi_tab + (size_t)tok*G3D + C;
    float r = sigm(gp[0]    + s0 + bhh[C]);
    float z = sigm(gp[HD]   + s1 + bhh[HD + C]);
    float n = ftanh(gp[2*HD] + r*(s2 + bhh[2*HD + C]));
    float hp = (float)h_s[b][C];
    float hnew = (1.f - z)*n + z*hp;
    const int gb = bg*32 + b;
    h_next[(size_t)gb*HD + C] = (f16)hnew;
    Hall[((size_t)l*BB + gb)*HD + C] = hnew;
  }
}

// ---------- Q = Hall @ WqT + bq -> f16 ; grid (128 rt, 8 nt), dot2 inner ----------
__global__ __launch_bounds__(256) void k_query(const float* __restrict__ Hall,
                                               const u32* __restrict__ Wq2,
                                               const float* __restrict__ bq,
                                               u16* __restrict__ Qh){
  const int rt = blockIdx.x, nt = blockIdx.y;
  const int tid = threadIdx.x;
  __shared__ u32 A2_s[16*68];
  __shared__ u32 B2_s[16*68];
  const int rq = tid >> 4, nq = tid & 15;
  const int i = tid >> 2, jj = tid & 3;
  const int i3 = tid >> 4, n4 = tid & 15;
  float acc[16] = {};
  for (int kc = 0; kc < 16; ++kc){
    __syncthreads();
    {
      const float* src = Hall + (size_t)(rt*64 + i)*HD + kc*32 + jj*8;
      float4 v0 = *(const float4*)src, v1 = *(const float4*)(src+4);
      A2_s[(jj*4+0)*68+i] = pkrtz(v0.x, v0.y);
      A2_s[(jj*4+1)*68+i] = pkrtz(v0.z, v0.w);
      A2_s[(jj*4+2)*68+i] = pkrtz(v1.x, v1.y);
      A2_s[(jj*4+3)*68+i] = pkrtz(v1.z, v1.w);
    }
    {
      uint4 v = *(const uint4*)(Wq2 + (size_t)(kc*16 + i3)*HD + nt*64 + n4*4);
      *(uint4*)&B2_s[i3*68 + n4*4] = v;
    }
    __syncthreads();
    INNER8P(rq, nq)
  }
  const int n0 = nt*64 + nq*4;
  float4 bv = *(const float4*)&bq[n0];
  #pragma unroll
  for (int r = 0; r < 4; ++r){
    u16* dst = Qh + (size_t)(rt*64 + rq*4 + r)*HD + n0;
    *(ushort4*)dst = hpk4(acc[r*4+0]+bv.x, acc[r*4+1]+bv.y,
                          acc[r*4+2]+bv.z, acc[r*4+3]+bv.w);
  }
}

// ---------- S[b][l][t] = Q[b,l,:] . enc[b,t,:] ; grid (128 b, 8 tt), dot2 ----------
__global__ __launch_bounds__(256) void k_scores(const u16* __restrict__ Qh,
                                                const u16* __restrict__ enc,
                                                float* __restrict__ Sbuf){
  const int bI = blockIdx.x, tt = blockIdx.y;
  const int tid = threadIdx.x;
  __shared__ u32 A2_s[16*68];
  __shared__ u32 B2_s[16*68];
  const int lq = tid >> 4, tq = tid & 15;
  const int i = tid >> 2, jj = tid & 3;
  float acc[16] = {};
  for (int kc = 0; kc < 16; ++kc){
    __syncthreads();
    {
      uint4 va = *(const uint4*)(Qh + ((size_t)i*BB + bI)*HD + kc*32 + jj*8);
      A2_s[(jj*4+0)*68+i] = va.x;
      A2_s[(jj*4+1)*68+i] = va.y;
      A2_s[(jj*4+2)*68+i] = va.z;
      A2_s[(jj*4+3)*68+i] = va.w;
    }
    {
      uint4 vb = *(const uint4*)(enc + ((size_t)bI*TT + tt*64 + i)*HD + kc*32 + jj*8);
      B2_s[(jj*4+0)*68+i] = vb.x;
      B2_s[(jj*4+1)*68+i] = vb.y;
      B2_s[(jj*4+2)*68+i] = vb.z;
      B2_s[(jj*4+3)*68+i] = vb.w;
    }
    __syncthreads();
    INNER8P(lq, tq)
  }
  #pragma unroll
  for (int r = 0; r < 4; ++r){
    float4 o = make_float4(acc[r*4+0],acc[r*4+1],acc[r*4+2],acc[r*4+3]);
    *(float4*)&Sbuf[((size_t)bI*LL + lq*4+r)*TT + tt*64 + tq*4] = o;
  }
}

// ---------- row softmax over t: P f16 ; grid 8192 x 64 ----------
__global__ __launch_bounds__(64) void k_softmax(const float* __restrict__ Sbuf,
                                                u16* __restrict__ Ph){
  const int row = blockIdx.x;
  const int lane = threadIdx.x;
  const float* s = Sbuf + (size_t)row*TT;
  float v[8]; float m = -1e30f;
  #pragma unroll
  for (int i = 0; i < 8; ++i){ v[i] = s[lane + i*64]; m = fmaxf(m, v[i]); }
  #pragma unroll
  for (int o = 32; o; o >>= 1) m = fmaxf(m, __shfl_xor(m, o));
  float Z = 0.f;
  #pragma unroll
  for (int i = 0; i < 8; ++i){ v[i] = fexp2(1.4426950408889634f*(v[i] - m)); Z += v[i]; }
  #pragma unroll
  for (int o = 32; o; o >>= 1) Z += __shfl_xor(Z, o);
  float inv = frcp(Z);
  u16* p = Ph + (size_t)row*TT;
  #pragma unroll
  for (int i = 0; i < 8; ++i) p[lane + i*64] = f2h(v[i]*inv);
}

// ---------- attn[b][t][l] = f32(P[b][l][t]) ; grid (128 b, 8 tt) ----------
__global__ __launch_bounds__(256) void k_attn_tr(const u16* __restrict__ Ph,
                                                 float* __restrict__ att){
  const int bI = blockIdx.x, tt = blockIdx.y;
  const int tid = threadIdx.x;
  __shared__ u16 tile[64][72];
  {
    const int i = tid >> 2, jj = tid & 3;
    #pragma unroll
    for (int rep = 0; rep < 2; ++rep){
      int ch = jj + rep*4;
      uint4 v = *(const uint4*)(Ph + ((size_t)bI*LL + i)*TT + tt*64 + ch*8);
      *(uint4*)&tile[i][ch*8] = v;
    }
  }
  __syncthreads();
  const int t = tid >> 2, jl = tid & 3;
  #pragma unroll
  for (int rep = 0; rep < 4; ++rep){
    int l0 = jl*16 + rep*4;
    float4 o;
    o.x = h2f(tile[l0+0][t]); o.y = h2f(tile[l0+1][t]);
    o.z = h2f(tile[l0+2][t]); o.w = h2f(tile[l0+3][t]);
    *(float4*)&att[((size_t)bI*TT + tt*64 + t)*LL + l0] = o;
  }
}

// ---------- ctx[l*128+b][n] = P[b,l,:] @ enc[b,:,n] -> f16 ; grid (128 b, 8 nt) ----------
__global__ __launch_bounds__(256) void k_ctx(const u16* __restrict__ Ph,
                                             const u16* __restrict__ enc,
                                             u16* __restrict__ ctxh){
  const int bI = blockIdx.x, nt = blockIdx.y;
  const int tid = threadIdx.x;
  __shared__ float A_s[32*68];
  __shared__ float B_s[32*68];
  const int lq = tid >> 4, nq = tid & 15;
  const int i = tid >> 2, jj = tid & 3;
  const int i2 = tid >> 3, jj2 = tid & 7;
  float acc[16] = {};
  for (int tc = 0; tc < 16; ++tc){
    __syncthreads();
    {
      float tmp[8];
      uint4 va = *(const uint4*)(Ph + ((size_t)bI*LL + i)*TT + tc*32 + jj*8);
      unp8h(va, tmp);
      #pragma unroll
      for (int m = 0; m < 8; ++m) A_s[(jj*8+m)*68 + i] = tmp[m];
    }
    {
      float tmp[8];
      uint4 vb = *(const uint4*)(enc + ((size_t)bI*TT + tc*32 + i2)*HD + nt*64 + jj2*8);
      unp8h(vb, tmp);
      *(float4*)&B_s[i2*68 + jj2*8]     = make_float4(tmp[0],tmp[1],tmp[2],tmp[3]);
      *(float4*)&B_s[i2*68 + jj2*8 + 4] = make_float4(tmp[4],tmp[5],tmp[6],tmp[7]);
    }
    __syncthreads();
    INNER16(lq, nq)
  }
  const int n0 = nt*64 + nq*4;
  #pragma unroll
  for (int r = 0; r < 4; ++r){
    int ll = lq*4 + r;
    u16* dst = ctxh + ((size_t)ll*BB + bI)*HD + n0;
    *(ushort4*)dst = hpk4(acc[r*4+0], acc[r*4+1], acc[r*4+2], acc[r*4+3]);
  }
}

// ---------- o = [Hall|ctx] @ WcT + bc ; grid (128 rt, 4 nt), dot2 ----------
__global__ __launch_bounds__(256) void k_outc(const float* __restrict__ Hall,
                                              const u16* __restrict__ ctxh,
                                              const u32* __restrict__ Wc2,
                                              const float* __restrict__ bc,
                                              float* __restrict__ obuf){
  const int rt = blockIdx.x, nt = blockIdx.y;
  const int tid = threadIdx.x;
  __shared__ u32 A2_s[16*68];
  __shared__ u32 B2_s[16*68];
  const int rq = tid >> 4, nq = tid & 15;
  const int i = tid >> 2, jj = tid & 3;
  const int i3 = tid >> 4, n4 = tid & 15;
  float acc[16] = {};
  for (int kc = 0; kc < 32; ++kc){
    __syncthreads();
    if (kc < 16){
      const float* src = Hall + (size_t)(rt*64 + i)*HD + kc*32 + jj*8;
      float4 v0 = *(const float4*)src, v1 = *(const float4*)(src+4);
      A2_s[(jj*4+0)*68+i] = pkrtz(v0.x, v0.y);
      A2_s[(jj*4+1)*68+i] = pkrtz(v0.z, v0.w);
      A2_s[(jj*4+2)*68+i] = pkrtz(v1.x, v1.y);
      A2_s[(jj*4+3)*68+i] = pkrtz(v1.z, v1.w);
    } else {
      uint4 v = *(const uint4*)(ctxh + (size_t)(rt*64 + i)*HD + (kc-16)*32 + jj*8);
      A2_s[(jj*4+0)*68+i] = v.x;
      A2_s[(jj*4+1)*68+i] = v.y;
      A2_s[(jj*4+2)*68+i] = v.z;
      A2_s[(jj*4+3)*68+i] = v.w;
    }
    {
      uint4 v = *(const uint4*)(Wc2 + (size_t)(kc*16 + i3)*256 + nt*64 + n4*4);
      *(uint4*)&B2_s[i3*68 + n4*4] = v;
    }
    __syncthreads();
    INNER8P(rq, nq)
  }
  const int n0 = nt*64 + nq*4;
  float4 bv = *(const float4*)&bc[n0];
  #pragma unroll
  for (int r = 0; r < 4; ++r){
    float4 o = make_float4(acc[r*4+0]+bv.x, acc[r*4+1]+bv.y,
                           acc[r*4+2]+bv.z, acc[r*4+3]+bv.w);
    *(float4*)&obuf[(size_t)(rt*64 + rq*4 + r)*256 + n0] = o;
  }
}

// ---------- logits = o @ Wf^T + bf ; grid 128 ----------
__global__ __launch_bounds__(256) void k_fc(const float* __restrict__ obuf,
                                            const float* __restrict__ Wf,
                                            const float* __restrict__ bfv,
                                            float* __restrict__ out_vec){
  const int rt = blockIdx.x;
  const int tid = threadIdx.x;
  __shared__ float w_s[30*260];
  for (int rr = 0; rr < 30; ++rr) w_s[rr*260 + tid] = Wf[(size_t)rr*256 + tid];
  __syncthreads();
  const int rl = tid >> 2, dq = tid & 3;
  const int r = rt*64 + rl;
  float acc[8] = {};
  for (int k = 0; k < 256; k += 4){
    float4 o4 = *(const float4*)&obuf[(size_t)r*256 + k];
    #pragma unroll
    for (int jq = 0; jq < 8; ++jq){
      int d = dq*8 + jq;
      if (d < 30){
        float4 w4 = *(const float4*)&w_s[d*260 + k];
        acc[jq] = fmaf(o4.x,w4.x,fmaf(o4.y,w4.y,fmaf(o4.z,w4.z,fmaf(o4.w,w4.w,acc[jq]))));
      }
    }
  }
  const int b = r & 127, l = r >> 7;
  #pragma unroll
  for (int jq = 0; jq < 8; ++jq){
    int d = dq*8 + jq;
    if (d < 30) out_vec[((size_t)b*LL + l)*NDICT + d] = acc[jq] + bfv[d];
  }
}

__global__ __launch_bounds__(256) void k_copy(const float* __restrict__ src,
                                              float* __restrict__ dst, int n){
  int i = blockIdx.x*256 + threadIdx.x;
  if (i < n) dst[i] = src[i];
}

extern "C" void kernel_launch(void* const* d_in, const int* in_sizes, int n_in,
                              void* d_out, int out_size, void* d_ws, size_t ws_size,
                              hipStream_t stream)
{
  const float* x     = (const float*)d_in[0];
  const int*   tgt   = (const int*)  d_in[1];
  const float* eWihF = (const float*)d_in[2];
  const float* eWhhF = (const float*)d_in[3];
  const float* ebihF = (const float*)d_in[4];
  const float* ebhhF = (const float*)d_in[5];
  const float* eWihB = (const float*)d_in[6];
  const float* eWhhB = (const float*)d_in[7];
  const float* ebihB = (const float*)d_in[8];
  const float* ebhhB = (const float*)d_in[9];
  const float* emb   = (const float*)d_in[10];
  const float* dWih  = (const float*)d_in[11];
  const float* dWhh  = (const float*)d_in[12];
  const float* dbih  = (const float*)d_in[13];
  const float* dbhh  = (const float*)d_in[14];
  const float* Wq    = (const float*)d_in[15];
  const float* bq    = (const float*)d_in[16];
  const float* Wc    = (const float*)d_in[17];
  const float* bc    = (const float*)d_in[18];
  const float* Wf    = (const float*)d_in[19];
  const float* bfv   = (const float*)d_in[20];

  char* w = (char*)d_ws;
  uint4* Wpenc = (uint4*)w; w += 786432;     // [2][32][768] uint4 f16
  uint4* Wpdec = (uint4*)w; w += 1572864;    // [64][24][64] uint4 f16 M-parallel
  u32*   Wq2   = (u32*)w;  w += 524288;      // [256 kp][512 n] f16 pairs
  u32*   Wc2   = (u32*)w;  w += 524288;      // [512 kp][256 n] f16 pairs
  float* gi_t  = (float*)w; w += 184320;
  float* h0buf = (float*)w; w += 262144;
  f16*   h16A  = (f16*)w; w += 131072;       // [128][512] f16
  f16*   h16B  = (f16*)w; w += 131072;
  float* Hall  = (float*)w; w += 16777216;
  u16*   Qh    = (u16*)w;                    // aliased: Ph reuses after k_scores
  u16*   Ph    = (u16*)w; w += 8388608;
  float* Sbuf  = (float*)w;                  // aliased over (ctxh | obuf)
  u16*   ctxh  = (u16*)w; w += 8388608;
  float* obuf  = (float*)w; w += 8388608;
  u16*   ench  = (u16*)w; w += 67108864;

  float* out     = (float*)d_out;
  float* out_vec = out;                              // [128][64][30]
  float* out_hT  = out + (size_t)BB*LL*NDICT;        // [1][128][512]
  float* out_att = out_hT + (size_t)BB*HD;           // [128][512][64]

  // prep
  k_prep_wenc<<<192, 256, 0, stream>>>(eWhhF, eWhhB, Wpenc);
  k_prep_wdec<<<384, 256, 0, stream>>>(dWhh, Wpdec);
  k_prep_pairT<<<512, 256, 0, stream>>>(Wq, Wq2, HD, HD);
  k_prep_pairT<<<512, 256, 0, stream>>>(Wc, Wc2, 256, 1024);
  k_gi_tab<<<dim3(NDICT, 6), 256, 0, stream>>>(emb, dWih, dbih, gi_t);

  // encoder: 256 independent recurrences, weights register-resident
  k_enc_p<<<BB*2, G3E, 0, stream>>>(x, Wpenc, eWihF, eWihB,
                                    ebihF, ebhhF, ebihB, ebhhB, ench, h0buf);

  // decoder recurrence: one launch per step, M-parallel
  k_h0cvt<<<256, 256, 0, stream>>>(h0buf, h16A);
  for (int l = 0; l < LL; ++l){
    const f16* hp = (l & 1) ? h16B : h16A;
    f16*       hn = (l & 1) ? h16A : h16B;
    k_dstep<<<256, 256, 0, stream>>>(tgt, gi_t, Wpdec, dbhh, hp, hn, Hall, l);
  }

  // batched post-recurrence pipeline
  k_query<<<dim3(128,8), 256, 0, stream>>>(Hall, Wq2, bq, Qh);
  k_scores<<<dim3(128,8), 256, 0, stream>>>(Qh, ench, Sbuf);
  k_softmax<<<BB*LL, 64, 0, stream>>>(Sbuf, Ph);
  k_attn_tr<<<dim3(128,8), 256, 0, stream>>>(Ph, out_att);
  k_ctx<<<dim3(128,8), 256, 0, stream>>>(Ph, ench, ctxh);
  k_outc<<<dim3(128,4), 256, 0, stream>>>(Hall, ctxh, Wc2, bc, obuf);
  k_fc<<<BB, 256, 0, stream>>>(obuf, Wf, bfv, out_vec);
  k_copy<<<(BB*HD+255)/256, 256, 0, stream>>>(Hall + (size_t)63*BB*HD, out_hT, BB*HD);
}

// Round 10
// 1212.505 us; speedup vs baseline: 3.2622x; 1.0077x over previous
//
#include <hip/hip_runtime.h>
#include <hip/hip_bf16.h>

typedef unsigned int u32;
typedef unsigned short u16;
typedef _Float16 f16;
typedef f16 f16x2 __attribute__((ext_vector_type(2)));

#define BB 128
#define TT 512
#define HE 256      // encoder hidden
#define G3E 768
#define HD 512      // decoder hidden (2H)
#define G3D 1536
#define LL 64
#define NDICT 30
#define EMBD 256

__device__ __forceinline__ float fexp2(float v){
#if __has_builtin(__builtin_amdgcn_exp2f)
  return __builtin_amdgcn_exp2f(v);
#else
  return exp2f(v);
#endif
}
__device__ __forceinline__ float frcp(float v){
#if __has_builtin(__builtin_amdgcn_rcpf)
  return __builtin_amdgcn_rcpf(v);
#else
  return 1.f/v;
#endif
}
__device__ __forceinline__ float sigm(float v){
  return frcp(1.f + fexp2(-1.4426950408889634f*v));
}
__device__ __forceinline__ float ftanh(float v){
  float e = fexp2(fminf(v, 40.f)*2.8853901631790583f);
  return (e - 1.f)*frcp(e + 1.f);
}
__device__ __forceinline__ u16 f2h(float f){ return __builtin_bit_cast(u16, (f16)f); }
__device__ __forceinline__ float h2f(u16 b){ return (float)__builtin_bit_cast(f16, b); }
__device__ __forceinline__ u32 pkh2(float a, float b){
  u16 lo = __builtin_bit_cast(u16, (f16)a);
  u16 hi = __builtin_bit_cast(u16, (f16)b);
  return (u32)lo | ((u32)hi << 16);
}
__device__ __forceinline__ u32 pkrtz(float a, float b){
  return __builtin_bit_cast(u32, __builtin_amdgcn_cvt_pkrtz(a, b));
}
__device__ __forceinline__ f16x2 bc2(u32 v){ return __builtin_bit_cast(f16x2, v); }

__device__ __forceinline__ void unp8h(uint4 v, float* d){
  f16x2 p;
  p = bc2(v.x); d[0]=(float)p.x; d[1]=(float)p.y;
  p = bc2(v.y); d[2]=(float)p.x; d[3]=(float)p.y;
  p = bc2(v.z); d[4]=(float)p.x; d[5]=(float)p.y;
  p = bc2(v.w); d[6]=(float)p.x; d[7]=(float)p.y;
}
__device__ __forceinline__ ushort4 hpk4(float a, float b, float c, float d){
  ushort4 r; r.x=f2h(a); r.y=f2h(b); r.z=f2h(c); r.w=f2h(d); return r;
}

// dot2: acc += a(2xf16) . b(2xf16), f32 accumulate
__device__ __forceinline__ float dot2f(u32 w, f16x2 h, float acc){
#if __has_builtin(__builtin_amdgcn_fdot2)
  return __builtin_amdgcn_fdot2(__builtin_bit_cast(f16x2, w), h, acc, false);
#else
  f16x2 wv = __builtin_bit_cast(f16x2, w);
  acc = fmaf((float)wv.x, (float)h.x, acc);
  return fmaf((float)wv.y, (float)h.y, acc);
#endif
}
__device__ __forceinline__ float dot2h(u32 a, u32 b, float acc){
  return dot2f(a, bc2(b), acc);
}
__device__ __forceinline__ void dot_u4(uint4 wv, uint4 hv, float& acc){
  acc = dot2f(wv.x, bc2(hv.x), acc);
  acc = dot2f(wv.y, bc2(hv.y), acc);
  acc = dot2f(wv.z, bc2(hv.z), acc);
  acc = dot2f(wv.w, bc2(hv.w), acc);
}

// f32 16-FMA inner (A_s/B_s [32][68] f32 k-major) — used by k_ctx
#define INNER16(Q0,Q1)                                              \
  _Pragma("unroll 8")                                               \
  for (int k = 0; k < 32; ++k){                                     \
    float4 a4 = *(const float4*)&A_s[k*68 + (Q0)*4];                \
    float4 b4 = *(const float4*)&B_s[k*68 + (Q1)*4];                \
    acc[0] =fmaf(a4.x,b4.x,acc[0]);  acc[1] =fmaf(a4.x,b4.y,acc[1]); \
    acc[2] =fmaf(a4.x,b4.z,acc[2]);  acc[3] =fmaf(a4.x,b4.w,acc[3]); \
    acc[4] =fmaf(a4.y,b4.x,acc[4]);  acc[5] =fmaf(a4.y,b4.y,acc[5]); \
    acc[6] =fmaf(a4.y,b4.z,acc[6]);  acc[7] =fmaf(a4.y,b4.w,acc[7]); \
    acc[8] =fmaf(a4.z,b4.x,acc[8]);  acc[9] =fmaf(a4.z,b4.y,acc[9]); \
    acc[10]=fmaf(a4.z,b4.z,acc[10]); acc[11]=fmaf(a4.z,b4.w,acc[11]);\
    acc[12]=fmaf(a4.w,b4.x,acc[12]); acc[13]=fmaf(a4.w,b4.y,acc[13]);\
    acc[14]=fmaf(a4.w,b4.z,acc[14]); acc[15]=fmaf(a4.w,b4.w,acc[15]);\
  }

// f16-pair dot2 inner (A2_s/B2_s u32[16][68], each u32 = 2 consecutive k)
#define INNER8P(Q0,Q1)                                                  \
  _Pragma("unroll")                                                     \
  for (int kp = 0; kp < 16; ++kp){                                      \
    uint4 a2 = *(const uint4*)&A2_s[kp*68 + (Q0)*4];                    \
    uint4 b2 = *(const uint4*)&B2_s[kp*68 + (Q1)*4];                    \
    acc[0] =dot2h(a2.x,b2.x,acc[0]);  acc[1] =dot2h(a2.x,b2.y,acc[1]);  \
    acc[2] =dot2h(a2.x,b2.z,acc[2]);  acc[3] =dot2h(a2.x,b2.w,acc[3]);  \
    acc[4] =dot2h(a2.y,b2.x,acc[4]);  acc[5] =dot2h(a2.y,b2.y,acc[5]);  \
    acc[6] =dot2h(a2.y,b2.z,acc[6]);  acc[7] =dot2h(a2.y,b2.w,acc[7]);  \
    acc[8] =dot2h(a2.z,b2.x,acc[8]);  acc[9] =dot2h(a2.z,b2.y,acc[9]);  \
    acc[10]=dot2h(a2.z,b2.z,acc[10]); acc[11]=dot2h(a2.z,b2.w,acc[11]); \
    acc[12]=dot2h(a2.w,b2.x,acc[12]); acc[13]=dot2h(a2.w,b2.y,acc[13]); \
    acc[14]=dot2h(a2.w,b2.z,acc[14]); acc[15]=dot2h(a2.w,b2.w,acc[15]); \
  }

// ---------- prep: pair-transposed f16 weights ----------
__global__ __launch_bounds__(256) void k_prep_pairT(const float* __restrict__ src,
                                                    u32* __restrict__ dst, int N, int K){
  int idx = blockIdx.x*256 + threadIdx.x;
  int KP = K >> 1;
  if (idx < N*KP){
    int n = idx / KP, kp = idx - n*KP;
    dst[(size_t)kp*N + n] = pkh2(src[(size_t)n*K + 2*kp], src[(size_t)n*K + 2*kp + 1]);
  }
}

// ---------- prep: encoder Whh -> f16 tile layout [dir][i 32][t 768] uint4 ----------
// t=(rg,cg): rg=t>>3, cg=t&7; i=(r,q): r=i>>2, q=i&3.
// value = row rg*8+r, cols [cg*32 + q*8, +8)
__global__ __launch_bounds__(256) void k_prep_wenc(const float* __restrict__ WF,
                                                   const float* __restrict__ WB,
                                                   uint4* __restrict__ dst){
  int idx = blockIdx.x*256 + threadIdx.x;   // 49152 = 2*32*768
  int dir = idx / 24576, rem = idx - dir*24576;
  int i = rem / 768, t = rem - i*768;
  int rg = t >> 3, cg = t & 7;
  int r = i >> 2, q = i & 3;
  const float* s = (dir ? WB : WF) + (size_t)(rg*8 + r)*HE + cg*32 + q*8;
  uint4 v; v.x=pkh2(s[0],s[1]); v.y=pkh2(s[2],s[3]); v.z=pkh2(s[4],s[5]); v.w=pkh2(s[6],s[7]);
  dst[idx] = v;
}

// ---------- prep: decoder Whh -> f16 M-parallel layout ----------
__global__ __launch_bounds__(256) void k_prep_wdec(const float* __restrict__ src,
                                                   uint4* __restrict__ dst){
  int idx = blockIdx.x*256 + threadIdx.x;   // 98304 = 64*24*64
  int lane = idx & 63;
  int ci = lane & 7, kq = lane >> 3;
  int rest = idx >> 6;                      // cg*24 + g*8 + u
  int u = rest & 7, g = (rest >> 3) % 3, cg = rest / 24;
  int row = g*512 + cg*8 + ci;
  int col = kq*64 + u*8;
  const float* s = src + (size_t)row*HD + col;
  uint4 v; v.x=pkh2(s[0],s[1]); v.y=pkh2(s[2],s[3]); v.z=pkh2(s[4],s[5]); v.w=pkh2(s[6],s[7]);
  dst[idx] = v;
}

// ---------- prep: gi[v][g] = emb[v]@dWih[g] + bih[g] ----------
__global__ __launch_bounds__(256) void k_gi_tab(const float* __restrict__ emb,
                                                const float* __restrict__ Wih,
                                                const float* __restrict__ bih,
                                                float* __restrict__ gi){
  int v = blockIdx.x, gy = blockIdx.y;   // grid (30, 6)
  int g = gy*256 + threadIdx.x;
  __shared__ float e_s[EMBD];
  if (threadIdx.x < EMBD) e_s[threadIdx.x] = emb[(size_t)v*EMBD + threadIdx.x];
  __syncthreads();
  const float4* w4 = (const float4*)(Wih + (size_t)g*EMBD);
  float acc = 0.f;
  #pragma unroll 8
  for (int k = 0; k < EMBD/4; ++k){
    float4 w = w4[k];
    float4 h = *(const float4*)&e_s[k*4];
    acc = fmaf(w.x,h.x,fmaf(w.y,h.y,fmaf(w.z,h.z,fmaf(w.w,h.w,acc))));
  }
  gi[(size_t)v*G3D + g] = acc + bih[g];
}

// ---------- prep: h0 f32 -> f16 ----------
__global__ __launch_bounds__(256) void k_h0cvt(const float* __restrict__ src,
                                               f16* __restrict__ dst){
  int i = blockIdx.x*256 + threadIdx.x;   // 65536
  dst[i] = (f16)src[i];
}

// ---------- encoder: one block per (batch, direction) ----------
// Col-split dot: thread (rg=tid>>3, cg=tid&7) owns an 8-row x 32-col weight
// tile (128 VGPR) and reads ONLY its 32-col h slice (4 b128 from padded
// h[8][40], bank-conflict-free) — 8x fewer LDS reads than row-split.
// 8 col-partials reduced across lanes cg=0..7 via 3-round shfl_xor butterfly;
// lane cg ends with row rg*8+cg == tid (matches its folded Wih/bias).
__global__ __launch_bounds__(768, 3) void k_enc_p(
    const float* __restrict__ x,
    const uint4* __restrict__ Wp,               // [2][32][768] uint4 tile layout
    const float* __restrict__ WihF, const float* __restrict__ WihB,
    const float* __restrict__ bihF, const float* __restrict__ bhhF,
    const float* __restrict__ bihB, const float* __restrict__ bhhB,
    u16* __restrict__ enc_out, float* __restrict__ h0out)
{
  const int b   = blockIdx.x >> 1;
  const int dir = blockIdx.x & 1;
  const int j   = threadIdx.x;
  const int cg  = j & 7;
  const float* Wih = dir ? WihB : WihF;
  const float* bih = dir ? bihB : bihF;
  const float* bhh = dir ? bhhB : bhhF;

  __shared__ __align__(16) f16 h_pad[8*40];  // 640 B, groups on distinct banks
  __shared__ float gh[2*HE];                 // finished r,z pre-acts
  __shared__ float gin_s[HE], ghn_s[HE];     // n-gate halves

  // weight tile -> 32 uint4 (128 VGPRs), coalesced
  uint4 w[32];
  {
    const uint4* wsrc = Wp + (size_t)dir*24576 + j;
    #pragma unroll
    for (int i = 0; i < 32; ++i) w[i] = wsrc[(size_t)i*768];
  }
  const float wv0r = Wih[j*2+0], wv1r = Wih[j*2+1];
  const float bi = bih[j], bh = bhh[j];
  const float badd = bi + bh;               // for r,z rows
  if (j < HE) h_pad[(j >> 5)*40 + (j & 31)] = (f16)0.f;
  float h_own = 0.f;
  const bool s0 = (cg & 1), s1 = (cg & 2), s2 = (cg & 4);
  __syncthreads();

  for (int t = 0; t < TT; ++t){
    const int tt = dir ? (TT-1-t) : t;
    const float x0 = x[((size_t)b*TT + tt)*2 + 0];
    const float x1 = x[((size_t)b*TT + tt)*2 + 1];

    // 4 b128 h reads (this thread's 32-col slice), 8 independent row-dots
    const uint4* hv = (const uint4*)(h_pad + cg*40);
    uint4 h0 = hv[0], h1 = hv[1], h2 = hv[2], h3 = hv[3];
    float p[8];
    #pragma unroll
    for (int r = 0; r < 8; ++r){
      float a = 0.f;
      dot_u4(w[r*4+0], h0, a);
      dot_u4(w[r*4+1], h1, a);
      dot_u4(w[r*4+2], h2, a);
      dot_u4(w[r*4+3], h3, a);
      p[r] = a;
    }
    // 8-lane transpose-reduce: lane cg ends with full sum for row rg*8+cg
    float q0 = (s0 ? p[1] : p[0]) + __shfl_xor(s0 ? p[0] : p[1], 1);
    float q1 = (s0 ? p[3] : p[2]) + __shfl_xor(s0 ? p[2] : p[3], 1);
    float q2 = (s0 ? p[5] : p[4]) + __shfl_xor(s0 ? p[4] : p[5], 1);
    float q3 = (s0 ? p[7] : p[6]) + __shfl_xor(s0 ? p[6] : p[7], 1);
    float r0 = (s1 ? q1 : q0) + __shfl_xor(s1 ? q0 : q1, 2);
    float r1 = (s1 ? q3 : q2) + __shfl_xor(s1 ? q2 : q3, 2);
    float tot = (s2 ? r1 : r0) + __shfl_xor(s2 ? r0 : r1, 4);

    const float xp = fmaf(wv0r, x0, wv1r*x1);
    if (j < 2*HE){
      gh[j] = tot + xp + badd;              // r,z: fully folded
    } else {
      ghn_s[j-2*HE] = tot + bh;
      gin_s[j-2*HE] = xp + bi;
    }
    __syncthreads();
    if (j < HE){
      float r = sigm(gh[j]);
      float z = sigm(gh[j+HE]);
      float n = ftanh(gin_s[j] + r*ghn_s[j]);
      float hnew = (1.f - z)*n + z*h_own;
      h_own = hnew;
      h_pad[(j >> 5)*40 + (j & 31)] = (f16)hnew;
      enc_out[((size_t)b*TT + tt)*HD + dir*HE + j] = f2h(hnew);
    }
    __syncthreads();
  }
  if (j < HE) h0out[(size_t)b*HD + dir*HE + j] = h_own;
}

// ---------- decoder: ONE STEP per launch, M-parallel ----------
__global__ __launch_bounds__(256, 2) void k_dstep(
    const int* __restrict__ tgt, const float* __restrict__ gi_tab,
    const uint4* __restrict__ Wd2, const float* __restrict__ bhh,
    const f16* __restrict__ h_prev, f16* __restrict__ h_next,
    float* __restrict__ Hall, int l)
{
  const int bg = blockIdx.x & 3, cg = blockIdx.x >> 2;
  const int tid = threadIdx.x;
  const int ci = tid & 7, kq = (tid >> 3) & 7, bq = tid >> 6;

  __shared__ __align__(16) f16 h_s[32][HD];       // 32 KB
  __shared__ float p_s[3][32][8][8];              // 24 KB [g][b][ci][kq]
  __shared__ int tok_s[32];

  uint4 w[24];
  {
    const uint4* wp = Wd2 + (size_t)cg*24*64 + (kq*8 + ci);
    #pragma unroll
    for (int i = 0; i < 24; ++i) w[i] = wp[(size_t)i*64];
  }
  {
    const uint4* hsrc = (const uint4*)(h_prev + (size_t)bg*32*HD);
    uint4* hdst = (uint4*)&h_s[0][0];
    #pragma unroll
    for (int i = 0; i < 8; ++i) hdst[tid + i*256] = hsrc[tid + i*256];
  }
  if (tid < 32) tok_s[tid] = (l == 0) ? 1 : tgt[(size_t)(bg*32 + tid)*LL + l - 1];
  __syncthreads();

  #pragma unroll
  for (int nb = 0; nb < 8; ++nb){
    const int b = bq*8 + nb;
    const uint4* hv = (const uint4*)&h_s[b][kq*64];
    float x0 = 0.f, x1 = 0.f, x2 = 0.f;
    #pragma unroll
    for (int u = 0; u < 8; ++u){
      uint4 hh = hv[u];
      dot_u4(w[u],      hh, x0);
      dot_u4(w[8 + u],  hh, x1);
      dot_u4(w[16 + u], hh, x2);
    }
    p_s[0][b][ci][kq] = x0;
    p_s[1][b][ci][kq] = x1;
    p_s[2][b][ci][kq] = x2;
  }
  __syncthreads();

  {
    const int b = tid >> 3, cl = tid & 7;
    const int C = cg*8 + cl;
    float s0 = 0.f, s1 = 0.f, s2 = 0.f;
    #pragma unroll
    for (int k = 0; k < 8; ++k){
      s0 += p_s[0][b][cl][k];
      s1 += p_s[1][b][cl][k];
      s2 += p_s[2][b][cl][k];
    }
    const int tok = tok_s[b];
    const float* gp = gi_tab + (size_t)tok*G3D + C;
    float r = sigm(gp[0]    + s0 + bhh[C]);
    float z = sigm(gp[HD]   + s1 + bhh[HD + C]);
    float n = ftanh(gp[2*HD] + r*(s2 + bhh[2*HD + C]));
    float hp = (float)h_s[b][C];
    float hnew = (1.f - z)*n + z*hp;
    const int gb = bg*32 + b;
    h_next[(size_t)gb*HD + C] = (f16)hnew;
    Hall[((size_t)l*BB + gb)*HD + C] = hnew;
  }
}

// ---------- Q = Hall @ WqT + bq -> f16 ; grid (128 rt, 8 nt), dot2 inner ----------
__global__ __launch_bounds__(256) void k_query(const float* __restrict__ Hall,
                                               const u32* __restrict__ Wq2,
                                               const float* __restrict__ bq,
                                               u16* __restrict__ Qh){
  const int rt = blockIdx.x, nt = blockIdx.y;
  const int tid = threadIdx.x;
  __shared__ u32 A2_s[16*68];
  __shared__ u32 B2_s[16*68];
  const int rq = tid >> 4, nq = tid & 15;
  const int i = tid >> 2, jj = tid & 3;
  const int i3 = tid >> 4, n4 = tid & 15;
  float acc[16] = {};
  for (int kc = 0; kc < 16; ++kc){
    __syncthreads();
    {
      const float* src = Hall + (size_t)(rt*64 + i)*HD + kc*32 + jj*8;
      float4 v0 = *(const float4*)src, v1 = *(const float4*)(src+4);
      A2_s[(jj*4+0)*68+i] = pkrtz(v0.x, v0.y);
      A2_s[(jj*4+1)*68+i] = pkrtz(v0.z, v0.w);
      A2_s[(jj*4+2)*68+i] = pkrtz(v1.x, v1.y);
      A2_s[(jj*4+3)*68+i] = pkrtz(v1.z, v1.w);
    }
    {
      uint4 v = *(const uint4*)(Wq2 + (size_t)(kc*16 + i3)*HD + nt*64 + n4*4);
      *(uint4*)&B2_s[i3*68 + n4*4] = v;
    }
    __syncthreads();
    INNER8P(rq, nq)
  }
  const int n0 = nt*64 + nq*4;
  float4 bv = *(const float4*)&bq[n0];
  #pragma unroll
  for (int r = 0; r < 4; ++r){
    u16* dst = Qh + (size_t)(rt*64 + rq*4 + r)*HD + n0;
    *(ushort4*)dst = hpk4(acc[r*4+0]+bv.x, acc[r*4+1]+bv.y,
                          acc[r*4+2]+bv.z, acc[r*4+3]+bv.w);
  }
}

// ---------- S[b][l][t] = Q[b,l,:] . enc[b,t,:] ; grid (128 b, 8 tt), dot2 ----------
__global__ __launch_bounds__(256) void k_scores(const u16* __restrict__ Qh,
                                                const u16* __restrict__ enc,
                                                float* __restrict__ Sbuf){
  const int bI = blockIdx.x, tt = blockIdx.y;
  const int tid = threadIdx.x;
  __shared__ u32 A2_s[16*68];
  __shared__ u32 B2_s[16*68];
  const int lq = tid >> 4, tq = tid & 15;
  const int i = tid >> 2, jj = tid & 3;
  float acc[16] = {};
  for (int kc = 0; kc < 16; ++kc){
    __syncthreads();
    {
      uint4 va = *(const uint4*)(Qh + ((size_t)i*BB + bI)*HD + kc*32 + jj*8);
      A2_s[(jj*4+0)*68+i] = va.x;
      A2_s[(jj*4+1)*68+i] = va.y;
      A2_s[(jj*4+2)*68+i] = va.z;
      A2_s[(jj*4+3)*68+i] = va.w;
    }
    {
      uint4 vb = *(const uint4*)(enc + ((size_t)bI*TT + tt*64 + i)*HD + kc*32 + jj*8);
      B2_s[(jj*4+0)*68+i] = vb.x;
      B2_s[(jj*4+1)*68+i] = vb.y;
      B2_s[(jj*4+2)*68+i] = vb.z;
      B2_s[(jj*4+3)*68+i] = vb.w;
    }
    __syncthreads();
    INNER8P(lq, tq)
  }
  #pragma unroll
  for (int r = 0; r < 4; ++r){
    float4 o = make_float4(acc[r*4+0],acc[r*4+1],acc[r*4+2],acc[r*4+3]);
    *(float4*)&Sbuf[((size_t)bI*LL + lq*4+r)*TT + tt*64 + tq*4] = o;
  }
}

// ---------- row softmax over t: P f16 ; grid 8192 x 64 ----------
__global__ __launch_bounds__(64) void k_softmax(const float* __restrict__ Sbuf,
                                                u16* __restrict__ Ph){
  const int row = blockIdx.x;
  const int lane = threadIdx.x;
  const float* s = Sbuf + (size_t)row*TT;
  float v[8]; float m = -1e30f;
  #pragma unroll
  for (int i = 0; i < 8; ++i){ v[i] = s[lane + i*64]; m = fmaxf(m, v[i]); }
  #pragma unroll
  for (int o = 32; o; o >>= 1) m = fmaxf(m, __shfl_xor(m, o));
  float Z = 0.f;
  #pragma unroll
  for (int i = 0; i < 8; ++i){ v[i] = fexp2(1.4426950408889634f*(v[i] - m)); Z += v[i]; }
  #pragma unroll
  for (int o = 32; o; o >>= 1) Z += __shfl_xor(Z, o);
  float inv = frcp(Z);
  u16* p = Ph + (size_t)row*TT;
  #pragma unroll
  for (int i = 0; i < 8; ++i) p[lane + i*64] = f2h(v[i]*inv);
}

// ---------- attn[b][t][l] = f32(P[b][l][t]) ; grid (128 b, 8 tt) ----------
__global__ __launch_bounds__(256) void k_attn_tr(const u16* __restrict__ Ph,
                                                 float* __restrict__ att){
  const int bI = blockIdx.x, tt = blockIdx.y;
  const int tid = threadIdx.x;
  __shared__ u16 tile[64][72];
  {
    const int i = tid >> 2, jj = tid & 3;
    #pragma unroll
    for (int rep = 0; rep < 2; ++rep){
      int ch = jj + rep*4;
      uint4 v = *(const uint4*)(Ph + ((size_t)bI*LL + i)*TT + tt*64 + ch*8);
      *(uint4*)&tile[i][ch*8] = v;
    }
  }
  __syncthreads();
  const int t = tid >> 2, jl = tid & 3;
  #pragma unroll
  for (int rep = 0; rep < 4; ++rep){
    int l0 = jl*16 + rep*4;
    float4 o;
    o.x = h2f(tile[l0+0][t]); o.y = h2f(tile[l0+1][t]);
    o.z = h2f(tile[l0+2][t]); o.w = h2f(tile[l0+3][t]);
    *(float4*)&att[((size_t)bI*TT + tt*64 + t)*LL + l0] = o;
  }
}

// ---------- ctx[l*128+b][n] = P[b,l,:] @ enc[b,:,n] -> f16 ; grid (128 b, 8 nt) ----------
__global__ __launch_bounds__(256) void k_ctx(const u16* __restrict__ Ph,
                                             const u16* __restrict__ enc,
                                             u16* __restrict__ ctxh){
  const int bI = blockIdx.x, nt = blockIdx.y;
  const int tid = threadIdx.x;
  __shared__ float A_s[32*68];
  __shared__ float B_s[32*68];
  const int lq = tid >> 4, nq = tid & 15;
  const int i = tid >> 2, jj = tid & 3;
  const int i2 = tid >> 3, jj2 = tid & 7;
  float acc[16] = {};
  for (int tc = 0; tc < 16; ++tc){
    __syncthreads();
    {
      float tmp[8];
      uint4 va = *(const uint4*)(Ph + ((size_t)bI*LL + i)*TT + tc*32 + jj*8);
      unp8h(va, tmp);
      #pragma unroll
      for (int m = 0; m < 8; ++m) A_s[(jj*8+m)*68 + i] = tmp[m];
    }
    {
      float tmp[8];
      uint4 vb = *(const uint4*)(enc + ((size_t)bI*TT + tc*32 + i2)*HD + nt*64 + jj2*8);
      unp8h(vb, tmp);
      *(float4*)&B_s[i2*68 + jj2*8]     = make_float4(tmp[0],tmp[1],tmp[2],tmp[3]);
      *(float4*)&B_s[i2*68 + jj2*8 + 4] = make_float4(tmp[4],tmp[5],tmp[6],tmp[7]);
    }
    __syncthreads();
    INNER16(lq, nq)
  }
  const int n0 = nt*64 + nq*4;
  #pragma unroll
  for (int r = 0; r < 4; ++r){
    int ll = lq*4 + r;
    u16* dst = ctxh + ((size_t)ll*BB + bI)*HD + n0;
    *(ushort4*)dst = hpk4(acc[r*4+0], acc[r*4+1], acc[r*4+2], acc[r*4+3]);
  }
}

// ---------- o = [Hall|ctx] @ WcT + bc ; grid (128 rt, 4 nt), dot2 ----------
__global__ __launch_bounds__(256) void k_outc(const float* __restrict__ Hall,
                                              const u16* __restrict__ ctxh,
                                              const u32* __restrict__ Wc2,
                                              const float* __restrict__ bc,
                                              float* __restrict__ obuf){
  const int rt = blockIdx.x, nt = blockIdx.y;
  const int tid = threadIdx.x;
  __shared__ u32 A2_s[16*68];
  __shared__ u32 B2_s[16*68];
  const int rq = tid >> 4, nq = tid & 15;
  const int i = tid >> 2, jj = tid & 3;
  const int i3 = tid >> 4, n4 = tid & 15;
  float acc[16] = {};
  for (int kc = 0; kc < 32; ++kc){
    __syncthreads();
    if (kc < 16){
      const float* src = Hall + (size_t)(rt*64 + i)*HD + kc*32 + jj*8;
      float4 v0 = *(const float4*)src, v1 = *(const float4*)(src+4);
      A2_s[(jj*4+0)*68+i] = pkrtz(v0.x, v0.y);
      A2_s[(jj*4+1)*68+i] = pkrtz(v0.z, v0.w);
      A2_s[(jj*4+2)*68+i] = pkrtz(v1.x, v1.y);
      A2_s[(jj*4+3)*68+i] = pkrtz(v1.z, v1.w);
    } else {
      uint4 v = *(const uint4*)(ctxh + (size_t)(rt*64 + i)*HD + (kc-16)*32 + jj*8);
      A2_s[(jj*4+0)*68+i] = v.x;
      A2_s[(jj*4+1)*68+i] = v.y;
      A2_s[(jj*4+2)*68+i] = v.z;
      A2_s[(jj*4+3)*68+i] = v.w;
    }
    {
      uint4 v = *(const uint4*)(Wc2 + (size_t)(kc*16 + i3)*256 + nt*64 + n4*4);
      *(uint4*)&B2_s[i3*68 + n4*4] = v;
    }
    __syncthreads();
    INNER8P(rq, nq)
  }
  const int n0 = nt*64 + nq*4;
  float4 bv = *(const float4*)&bc[n0];
  #pragma unroll
  for (int r = 0; r < 4; ++r){
    float4 o = make_float4(acc[r*4+0]+bv.x, acc[r*4+1]+bv.y,
                           acc[r*4+2]+bv.z, acc[r*4+3]+bv.w);
    *(float4*)&obuf[(size_t)(rt*64 + rq*4 + r)*256 + n0] = o;
  }
}

// ---------- logits = o @ Wf^T + bf ; grid 128 ----------
__global__ __launch_bounds__(256) void k_fc(const float* __restrict__ obuf,
                                            const float* __restrict__ Wf,
                                            const float* __restrict__ bfv,
                                            float* __restrict__ out_vec){
  const int rt = blockIdx.x;
  const int tid = threadIdx.x;
  __shared__ float w_s[30*260];
  for (int rr = 0; rr < 30; ++rr) w_s[rr*260 + tid] = Wf[(size_t)rr*256 + tid];
  __syncthreads();
  const int rl = tid >> 2, dq = tid & 3;
  const int r = rt*64 + rl;
  float acc[8] = {};
  for (int k = 0; k < 256; k += 4){
    float4 o4 = *(const float4*)&obuf[(size_t)r*256 + k];
    #pragma unroll
    for (int jq = 0; jq < 8; ++jq){
      int d = dq*8 + jq;
      if (d < 30){
        float4 w4 = *(const float4*)&w_s[d*260 + k];
        acc[jq] = fmaf(o4.x,w4.x,fmaf(o4.y,w4.y,fmaf(o4.z,w4.z,fmaf(o4.w,w4.w,acc[jq]))));
      }
    }
  }
  const int b = r & 127, l = r >> 7;
  #pragma unroll
  for (int jq = 0; jq < 8; ++jq){
    int d = dq*8 + jq;
    if (d < 30) out_vec[((size_t)b*LL + l)*NDICT + d] = acc[jq] + bfv[d];
  }
}

__global__ __launch_bounds__(256) void k_copy(const float* __restrict__ src,
                                              float* __restrict__ dst, int n){
  int i = blockIdx.x*256 + threadIdx.x;
  if (i < n) dst[i] = src[i];
}

extern "C" void kernel_launch(void* const* d_in, const int* in_sizes, int n_in,
                              void* d_out, int out_size, void* d_ws, size_t ws_size,
                              hipStream_t stream)
{
  const float* x     = (const float*)d_in[0];
  const int*   tgt   = (const int*)  d_in[1];
  const float* eWihF = (const float*)d_in[2];
  const float* eWhhF = (const float*)d_in[3];
  const float* ebihF = (const float*)d_in[4];
  const float* ebhhF = (const float*)d_in[5];
  const float* eWihB = (const float*)d_in[6];
  const float* eWhhB = (const float*)d_in[7];
  const float* ebihB = (const float*)d_in[8];
  const float* ebhhB = (const float*)d_in[9];
  const float* emb   = (const float*)d_in[10];
  const float* dWih  = (const float*)d_in[11];
  const float* dWhh  = (const float*)d_in[12];
  const float* dbih  = (const float*)d_in[13];
  const float* dbhh  = (const float*)d_in[14];
  const float* Wq    = (const float*)d_in[15];
  const float* bq    = (const float*)d_in[16];
  const float* Wc    = (const float*)d_in[17];
  const float* bc    = (const float*)d_in[18];
  const float* Wf    = (const float*)d_in[19];
  const float* bfv   = (const float*)d_in[20];

  char* w = (char*)d_ws;
  uint4* Wpenc = (uint4*)w; w += 786432;     // [2][32][768] uint4 f16 tile layout
  uint4* Wpdec = (uint4*)w; w += 1572864;    // [64][24][64] uint4 f16 M-parallel
  u32*   Wq2   = (u32*)w;  w += 524288;      // [256 kp][512 n] f16 pairs
  u32*   Wc2   = (u32*)w;  w += 524288;      // [512 kp][256 n] f16 pairs
  float* gi_t  = (float*)w; w += 184320;
  float* h0buf = (float*)w; w += 262144;
  f16*   h16A  = (f16*)w; w += 131072;       // [128][512] f16
  f16*   h16B  = (f16*)w; w += 131072;
  float* Hall  = (float*)w; w += 16777216;
  u16*   Qh    = (u16*)w;                    // aliased: Ph reuses after k_scores
  u16*   Ph    = (u16*)w; w += 8388608;
  float* Sbuf  = (float*)w;                  // aliased over (ctxh | obuf)
  u16*   ctxh  = (u16*)w; w += 8388608;
  float* obuf  = (float*)w; w += 8388608;
  u16*   ench  = (u16*)w; w += 67108864;

  float* out     = (float*)d_out;
  float* out_vec = out;                              // [128][64][30]
  float* out_hT  = out + (size_t)BB*LL*NDICT;        // [1][128][512]
  float* out_att = out_hT + (size_t)BB*HD;           // [128][512][64]

  // prep
  k_prep_wenc<<<192, 256, 0, stream>>>(eWhhF, eWhhB, Wpenc);
  k_prep_wdec<<<384, 256, 0, stream>>>(dWhh, Wpdec);
  k_prep_pairT<<<512, 256, 0, stream>>>(Wq, Wq2, HD, HD);
  k_prep_pairT<<<512, 256, 0, stream>>>(Wc, Wc2, 256, 1024);
  k_gi_tab<<<dim3(NDICT, 6), 256, 0, stream>>>(emb, dWih, dbih, gi_t);

  // encoder: 256 independent recurrences, col-split dot + shfl butterfly
  k_enc_p<<<BB*2, G3E, 0, stream>>>(x, Wpenc, eWihF, eWihB,
                                    ebihF, ebhhF, ebihB, ebhhB, ench, h0buf);

  // decoder recurrence: one launch per step, M-parallel
  k_h0cvt<<<256, 256, 0, stream>>>(h0buf, h16A);
  for (int l = 0; l < LL; ++l){
    const f16* hp = (l & 1) ? h16B : h16A;
    f16*       hn = (l & 1) ? h16A : h16B;
    k_dstep<<<256, 256, 0, stream>>>(tgt, gi_t, Wpdec, dbhh, hp, hn, Hall, l);
  }

  // batched post-recurrence pipeline
  k_query<<<dim3(128,8), 256, 0, stream>>>(Hall, Wq2, bq, Qh);
  k_scores<<<dim3(128,8), 256, 0, stream>>>(Qh, ench, Sbuf);
  k_softmax<<<BB*LL, 64, 0, stream>>>(Sbuf, Ph);
  k_attn_tr<<<dim3(128,8), 256, 0, stream>>>(Ph, out_att);
  k_ctx<<<dim3(128,8), 256, 0, stream>>>(Ph, ench, ctxh);
  k_outc<<<dim3(128,4), 256, 0, stream>>>(Hall, ctxh, Wc2, bc, obuf);
  k_fc<<<BB, 256, 0, stream>>>(obuf, Wf, bfv, out_vec);
  k_copy<<<(BB*HD+255)/256, 256, 0, stream>>>(Hall + (size_t)63*BB*HD, out_hT, BB*HD);
}

// Round 11
// 1195.242 us; speedup vs baseline: 3.3094x; 1.0144x over previous
//
#include <hip/hip_runtime.h>
#include <hip/hip_bf16.h>

typedef unsigned int u32;
typedef unsigned short u16;
typedef _Float16 f16;
typedef f16 f16x2 __attribute__((ext_vector_type(2)));

#define BB 128
#define TT 512
#define HE 256      // encoder hidden
#define G3E 768
#define HD 512      // decoder hidden (2H)
#define G3D 1536
#define LL 64
#define NDICT 30
#define EMBD 256

__device__ __forceinline__ float fexp2(float v){
#if __has_builtin(__builtin_amdgcn_exp2f)
  return __builtin_amdgcn_exp2f(v);
#else
  return exp2f(v);
#endif
}
__device__ __forceinline__ float frcp(float v){
#if __has_builtin(__builtin_amdgcn_rcpf)
  return __builtin_amdgcn_rcpf(v);
#else
  return 1.f/v;
#endif
}
__device__ __forceinline__ float sigm(float v){
  return frcp(1.f + fexp2(-1.4426950408889634f*v));
}
__device__ __forceinline__ float ftanh(float v){
  float e = fexp2(fminf(v, 40.f)*2.8853901631790583f);
  return (e - 1.f)*frcp(e + 1.f);
}
__device__ __forceinline__ u16 f2h(float f){ return __builtin_bit_cast(u16, (f16)f); }
__device__ __forceinline__ float h2f(u16 b){ return (float)__builtin_bit_cast(f16, b); }
__device__ __forceinline__ u32 pkh2(float a, float b){
  u16 lo = __builtin_bit_cast(u16, (f16)a);
  u16 hi = __builtin_bit_cast(u16, (f16)b);
  return (u32)lo | ((u32)hi << 16);
}
__device__ __forceinline__ u32 pkrtz(float a, float b){
  return __builtin_bit_cast(u32, __builtin_amdgcn_cvt_pkrtz(a, b));
}
__device__ __forceinline__ f16x2 bc2(u32 v){ return __builtin_bit_cast(f16x2, v); }

__device__ __forceinline__ void unp8h(uint4 v, float* d){
  f16x2 p;
  p = bc2(v.x); d[0]=(float)p.x; d[1]=(float)p.y;
  p = bc2(v.y); d[2]=(float)p.x; d[3]=(float)p.y;
  p = bc2(v.z); d[4]=(float)p.x; d[5]=(float)p.y;
  p = bc2(v.w); d[6]=(float)p.x; d[7]=(float)p.y;
}
__device__ __forceinline__ ushort4 hpk4(float a, float b, float c, float d){
  ushort4 r; r.x=f2h(a); r.y=f2h(b); r.z=f2h(c); r.w=f2h(d); return r;
}

// dot2: acc += a(2xf16) . b(2xf16), f32 accumulate
__device__ __forceinline__ float dot2f(u32 w, f16x2 h, float acc){
#if __has_builtin(__builtin_amdgcn_fdot2)
  return __builtin_amdgcn_fdot2(__builtin_bit_cast(f16x2, w), h, acc, false);
#else
  f16x2 wv = __builtin_bit_cast(f16x2, w);
  acc = fmaf((float)wv.x, (float)h.x, acc);
  return fmaf((float)wv.y, (float)h.y, acc);
#endif
}
__device__ __forceinline__ float dot2h(u32 a, u32 b, float acc){
  return dot2f(a, bc2(b), acc);
}
__device__ __forceinline__ void dot_u4(uint4 wv, uint4 hv, float& acc){
  acc = dot2f(wv.x, bc2(hv.x), acc);
  acc = dot2f(wv.y, bc2(hv.y), acc);
  acc = dot2f(wv.z, bc2(hv.z), acc);
  acc = dot2f(wv.w, bc2(hv.w), acc);
}

// f32 16-FMA inner (A_s/B_s [32][68] f32 k-major) — used by k_ctx
#define INNER16(Q0,Q1)                                              \
  _Pragma("unroll 8")                                               \
  for (int k = 0; k < 32; ++k){                                     \
    float4 a4 = *(const float4*)&A_s[k*68 + (Q0)*4];                \
    float4 b4 = *(const float4*)&B_s[k*68 + (Q1)*4];                \
    acc[0] =fmaf(a4.x,b4.x,acc[0]);  acc[1] =fmaf(a4.x,b4.y,acc[1]); \
    acc[2] =fmaf(a4.x,b4.z,acc[2]);  acc[3] =fmaf(a4.x,b4.w,acc[3]); \
    acc[4] =fmaf(a4.y,b4.x,acc[4]);  acc[5] =fmaf(a4.y,b4.y,acc[5]); \
    acc[6] =fmaf(a4.y,b4.z,acc[6]);  acc[7] =fmaf(a4.y,b4.w,acc[7]); \
    acc[8] =fmaf(a4.z,b4.x,acc[8]);  acc[9] =fmaf(a4.z,b4.y,acc[9]); \
    acc[10]=fmaf(a4.z,b4.z,acc[10]); acc[11]=fmaf(a4.z,b4.w,acc[11]);\
    acc[12]=fmaf(a4.w,b4.x,acc[12]); acc[13]=fmaf(a4.w,b4.y,acc[13]);\
    acc[14]=fmaf(a4.w,b4.z,acc[14]); acc[15]=fmaf(a4.w,b4.w,acc[15]);\
  }

// f16-pair dot2 inner (A2_s/B2_s u32[16][68], each u32 = 2 consecutive k)
#define INNER8P(Q0,Q1)                                                  \
  _Pragma("unroll")                                                     \
  for (int kp = 0; kp < 16; ++kp){                                      \
    uint4 a2 = *(const uint4*)&A2_s[kp*68 + (Q0)*4];                    \
    uint4 b2 = *(const uint4*)&B2_s[kp*68 + (Q1)*4];                    \
    acc[0] =dot2h(a2.x,b2.x,acc[0]);  acc[1] =dot2h(a2.x,b2.y,acc[1]);  \
    acc[2] =dot2h(a2.x,b2.z,acc[2]);  acc[3] =dot2h(a2.x,b2.w,acc[3]);  \
    acc[4] =dot2h(a2.y,b2.x,acc[4]);  acc[5] =dot2h(a2.y,b2.y,acc[5]);  \
    acc[6] =dot2h(a2.y,b2.z,acc[6]);  acc[7] =dot2h(a2.y,b2.w,acc[7]);  \
    acc[8] =dot2h(a2.z,b2.x,acc[8]);  acc[9] =dot2h(a2.z,b2.y,acc[9]);  \
    acc[10]=dot2h(a2.z,b2.z,acc[10]); acc[11]=dot2h(a2.z,b2.w,acc[11]); \
    acc[12]=dot2h(a2.w,b2.x,acc[12]); acc[13]=dot2h(a2.w,b2.y,acc[13]); \
    acc[14]=dot2h(a2.w,b2.z,acc[14]); acc[15]=dot2h(a2.w,b2.w,acc[15]); \
  }

// ---------- prep: pair-transposed f16 weights ----------
__global__ __launch_bounds__(256) void k_prep_pairT(const float* __restrict__ src,
                                                    u32* __restrict__ dst, int N, int K){
  int idx = blockIdx.x*256 + threadIdx.x;
  int KP = K >> 1;
  if (idx < N*KP){
    int n = idx / KP, kp = idx - n*KP;
    dst[(size_t)kp*N + n] = pkh2(src[(size_t)n*K + 2*kp], src[(size_t)n*K + 2*kp + 1]);
  }
}

// ---------- prep: encoder Whh -> f16 tile layout [dir][i 32][t 768] uint4 ----------
__global__ __launch_bounds__(256) void k_prep_wenc(const float* __restrict__ WF,
                                                   const float* __restrict__ WB,
                                                   uint4* __restrict__ dst){
  int idx = blockIdx.x*256 + threadIdx.x;   // 49152 = 2*32*768
  int dir = idx / 24576, rem = idx - dir*24576;
  int i = rem / 768, t = rem - i*768;
  int rg = t >> 3, cg = t & 7;
  int r = i >> 2, q = i & 3;
  const float* s = (dir ? WB : WF) + (size_t)(rg*8 + r)*HE + cg*32 + q*8;
  uint4 v; v.x=pkh2(s[0],s[1]); v.y=pkh2(s[2],s[3]); v.z=pkh2(s[4],s[5]); v.w=pkh2(s[6],s[7]);
  dst[idx] = v;
}

// ---------- prep: decoder Whh -> f16 M-parallel layout ----------
__global__ __launch_bounds__(256) void k_prep_wdec(const float* __restrict__ src,
                                                   uint4* __restrict__ dst){
  int idx = blockIdx.x*256 + threadIdx.x;   // 98304 = 64*24*64
  int lane = idx & 63;
  int ci = lane & 7, kq = lane >> 3;
  int rest = idx >> 6;                      // cg*24 + g*8 + u
  int u = rest & 7, g = (rest >> 3) % 3, cg = rest / 24;
  int row = g*512 + cg*8 + ci;
  int col = kq*64 + u*8;
  const float* s = src + (size_t)row*HD + col;
  uint4 v; v.x=pkh2(s[0],s[1]); v.y=pkh2(s[2],s[3]); v.z=pkh2(s[4],s[5]); v.w=pkh2(s[6],s[7]);
  dst[idx] = v;
}

// ---------- prep: gi[v][g] = emb[v]@dWih[g] + bih[g] ----------
__global__ __launch_bounds__(256) void k_gi_tab(const float* __restrict__ emb,
                                                const float* __restrict__ Wih,
                                                const float* __restrict__ bih,
                                                float* __restrict__ gi){
  int v = blockIdx.x, gy = blockIdx.y;   // grid (30, 6)
  int g = gy*256 + threadIdx.x;
  __shared__ float e_s[EMBD];
  if (threadIdx.x < EMBD) e_s[threadIdx.x] = emb[(size_t)v*EMBD + threadIdx.x];
  __syncthreads();
  const float4* w4 = (const float4*)(Wih + (size_t)g*EMBD);
  float acc = 0.f;
  #pragma unroll 8
  for (int k = 0; k < EMBD/4; ++k){
    float4 w = w4[k];
    float4 h = *(const float4*)&e_s[k*4];
    acc = fmaf(w.x,h.x,fmaf(w.y,h.y,fmaf(w.z,h.z,fmaf(w.w,h.w,acc))));
  }
  gi[(size_t)v*G3D + g] = acc + bih[g];
}

// ---------- prep: h0 f32 -> f16 ----------
__global__ __launch_bounds__(256) void k_h0cvt(const float* __restrict__ src,
                                               f16* __restrict__ dst){
  int i = blockIdx.x*256 + threadIdx.x;   // 65536
  dst[i] = (f16)src[i];
}

// ---------- encoder: one block per (batch, direction) ----------
__global__ __launch_bounds__(768, 3) void k_enc_p(
    const float* __restrict__ x,
    const uint4* __restrict__ Wp,               // [2][32][768] uint4 tile layout
    const float* __restrict__ WihF, const float* __restrict__ WihB,
    const float* __restrict__ bihF, const float* __restrict__ bhhF,
    const float* __restrict__ bihB, const float* __restrict__ bhhB,
    u16* __restrict__ enc_out, float* __restrict__ h0out)
{
  const int b   = blockIdx.x >> 1;
  const int dir = blockIdx.x & 1;
  const int j   = threadIdx.x;
  const int cg  = j & 7;
  const float* Wih = dir ? WihB : WihF;
  const float* bih = dir ? bihB : bihF;
  const float* bhh = dir ? bhhB : bhhF;

  __shared__ __align__(16) f16 h_pad[8*40];  // 640 B, groups on distinct banks
  __shared__ float gh[2*HE];                 // finished r,z pre-acts
  __shared__ float gin_s[HE], ghn_s[HE];     // n-gate halves

  // weight tile -> 32 uint4 (128 VGPRs), coalesced
  uint4 w[32];
  {
    const uint4* wsrc = Wp + (size_t)dir*24576 + j;
    #pragma unroll
    for (int i = 0; i < 32; ++i) w[i] = wsrc[(size_t)i*768];
  }
  const float wv0r = Wih[j*2+0], wv1r = Wih[j*2+1];
  const float bi = bih[j], bh = bhh[j];
  const float badd = bi + bh;               // for r,z rows
  if (j < HE) h_pad[(j >> 5)*40 + (j & 31)] = (f16)0.f;
  float h_own = 0.f;
  const bool s0 = (cg & 1), s1 = (cg & 2), s2 = (cg & 4);
  __syncthreads();

  for (int t = 0; t < TT; ++t){
    const int tt = dir ? (TT-1-t) : t;
    const float x0 = x[((size_t)b*TT + tt)*2 + 0];
    const float x1 = x[((size_t)b*TT + tt)*2 + 1];

    // 4 b128 h reads (this thread's 32-col slice), 8 independent row-dots
    const uint4* hv = (const uint4*)(h_pad + cg*40);
    uint4 h0 = hv[0], h1 = hv[1], h2 = hv[2], h3 = hv[3];
    float p[8];
    #pragma unroll
    for (int r = 0; r < 8; ++r){
      float a = 0.f;
      dot_u4(w[r*4+0], h0, a);
      dot_u4(w[r*4+1], h1, a);
      dot_u4(w[r*4+2], h2, a);
      dot_u4(w[r*4+3], h3, a);
      p[r] = a;
    }
    // 8-lane transpose-reduce: lane cg ends with full sum for row rg*8+cg
    float q0 = (s0 ? p[1] : p[0]) + __shfl_xor(s0 ? p[0] : p[1], 1);
    float q1 = (s0 ? p[3] : p[2]) + __shfl_xor(s0 ? p[2] : p[3], 1);
    float q2 = (s0 ? p[5] : p[4]) + __shfl_xor(s0 ? p[4] : p[5], 1);
    float q3 = (s0 ? p[7] : p[6]) + __shfl_xor(s0 ? p[6] : p[7], 1);
    float r0 = (s1 ? q1 : q0) + __shfl_xor(s1 ? q0 : q1, 2);
    float r1 = (s1 ? q3 : q2) + __shfl_xor(s1 ? q2 : q3, 2);
    float tot = (s2 ? r1 : r0) + __shfl_xor(s2 ? r0 : r1, 4);

    const float xp = fmaf(wv0r, x0, wv1r*x1);
    if (j < 2*HE){
      gh[j] = tot + xp + badd;              // r,z: fully folded
    } else {
      ghn_s[j-2*HE] = tot + bh;
      gin_s[j-2*HE] = xp + bi;
    }
    __syncthreads();
    if (j < HE){
      float r = sigm(gh[j]);
      float z = sigm(gh[j+HE]);
      float n = ftanh(gin_s[j] + r*ghn_s[j]);
      float hnew = (1.f - z)*n + z*h_own;
      h_own = hnew;
      h_pad[(j >> 5)*40 + (j & 31)] = (f16)hnew;
      enc_out[((size_t)b*TT + tt)*HD + dir*HE + j] = f2h(hnew);
    }
    __syncthreads();
  }
  if (j < HE) h0out[(size_t)b*HD + dir*HE + j] = h_own;
}

// ---------- decoder: ONE STEP per launch, M-parallel ----------
// grid 512 = (bg 8) x (cg 64); block 256 thr; 16 batches x 8 cols per block.
// LDS ~32 KB -> 2+ blocks/CU (8 waves) so LDS reads overlap dot2 VALU.
// h_s[b][kq][72]: segment stride 72 f16 = 144 B -> kq slices hit disjoint
// bank groups 4kq..4kq+3 (conflict-free b128 reads; ci lanes broadcast).
__global__ __launch_bounds__(256, 2) void k_dstep(
    const int* __restrict__ tgt, const float* __restrict__ gi_tab,
    const uint4* __restrict__ Wd2, const float* __restrict__ bhh,
    const f16* __restrict__ h_prev, f16* __restrict__ h_next,
    float* __restrict__ Hall, int l)
{
  const int bg = blockIdx.x & 7, cg = blockIdx.x >> 3;
  const int tid = threadIdx.x;
  const int ci = tid & 7, kq = (tid >> 3) & 7, bq = tid >> 6;

  __shared__ __align__(16) f16 h_s[16][8][72];    // 18.4 KB, padded segments
  __shared__ float p_s[3][16][8][9];              // 13.8 KB [g][b][ci][kq+pad]
  __shared__ int tok_s[16];

  // weights -> 24 uint4 regs (lane-coalesced layout)
  uint4 w[24];
  {
    const uint4* wp = Wd2 + (size_t)cg*24*64 + (kq*8 + ci);
    #pragma unroll
    for (int i = 0; i < 24; ++i) w[i] = wp[(size_t)i*64];
  }
  // stage h tile (16 batches x 512 f16 = 1024 uint4) into padded layout
  {
    const uint4* hsrc = (const uint4*)(h_prev + (size_t)bg*16*HD);
    #pragma unroll
    for (int i = 0; i < 4; ++i){
      int idx = tid + i*256;
      int b = idx >> 6, w4 = idx & 63;
      int kq2 = w4 >> 3, off = w4 & 7;
      *(uint4*)&h_s[b][kq2][off*8] = hsrc[idx];
    }
  }
  if (tid < 16) tok_s[tid] = (l == 0) ? 1 : tgt[(size_t)(bg*16 + tid)*LL + l - 1];
  __syncthreads();

  // partial dots: 4 batches x 3 gates over this thread's 64-wide k-segment
  #pragma unroll
  for (int nb = 0; nb < 4; ++nb){
    const int b = bq*4 + nb;
    const uint4* hv = (const uint4*)&h_s[b][kq][0];
    float x0 = 0.f, x1 = 0.f, x2 = 0.f;
    #pragma unroll
    for (int u = 0; u < 8; ++u){
      uint4 hh = hv[u];
      dot_u4(w[u],      hh, x0);
      dot_u4(w[8 + u],  hh, x1);
      dot_u4(w[16 + u], hh, x2);
    }
    p_s[0][b][ci][kq] = x0;
    p_s[1][b][ci][kq] = x1;
    p_s[2][b][ci][kq] = x2;
  }
  __syncthreads();

  // reduce over kq + gates: 128 threads = (b=tid>>3, cl=tid&7)
  if (tid < 128){
    const int b = tid >> 3, cl = tid & 7;
    const int C = cg*8 + cl;
    float s0 = 0.f, s1 = 0.f, s2 = 0.f;
    #pragma unroll
    for (int k = 0; k < 8; ++k){
      s0 += p_s[0][b][cl][k];
      s1 += p_s[1][b][cl][k];
      s2 += p_s[2][b][cl][k];
    }
    const int tok = tok_s[b];
    const float* gp = gi_tab + (size_t)tok*G3D + C;
    float r = sigm(gp[0]    + s0 + bhh[C]);
    float z = sigm(gp[HD]   + s1 + bhh[HD + C]);
    float n = ftanh(gp[2*HD] + r*(s2 + bhh[2*HD + C]));
    float hp = (float)h_s[b][C >> 6][C & 63];
    float hnew = (1.f - z)*n + z*hp;
    const int gb = bg*16 + b;
    h_next[(size_t)gb*HD + C] = (f16)hnew;
    Hall[((size_t)l*BB + gb)*HD + C] = hnew;
  }
}

// ---------- Q = Hall @ WqT + bq -> f16 ; grid (128 rt, 8 nt), dot2 inner ----------
__global__ __launch_bounds__(256) void k_query(const float* __restrict__ Hall,
                                               const u32* __restrict__ Wq2,
                                               const float* __restrict__ bq,
                                               u16* __restrict__ Qh){
  const int rt = blockIdx.x, nt = blockIdx.y;
  const int tid = threadIdx.x;
  __shared__ u32 A2_s[16*68];
  __shared__ u32 B2_s[16*68];
  const int rq = tid >> 4, nq = tid & 15;
  const int i = tid >> 2, jj = tid & 3;
  const int i3 = tid >> 4, n4 = tid & 15;
  float acc[16] = {};
  for (int kc = 0; kc < 16; ++kc){
    __syncthreads();
    {
      const float* src = Hall + (size_t)(rt*64 + i)*HD + kc*32 + jj*8;
      float4 v0 = *(const float4*)src, v1 = *(const float4*)(src+4);
      A2_s[(jj*4+0)*68+i] = pkrtz(v0.x, v0.y);
      A2_s[(jj*4+1)*68+i] = pkrtz(v0.z, v0.w);
      A2_s[(jj*4+2)*68+i] = pkrtz(v1.x, v1.y);
      A2_s[(jj*4+3)*68+i] = pkrtz(v1.z, v1.w);
    }
    {
      uint4 v = *(const uint4*)(Wq2 + (size_t)(kc*16 + i3)*HD + nt*64 + n4*4);
      *(uint4*)&B2_s[i3*68 + n4*4] = v;
    }
    __syncthreads();
    INNER8P(rq, nq)
  }
  const int n0 = nt*64 + nq*4;
  float4 bv = *(const float4*)&bq[n0];
  #pragma unroll
  for (int r = 0; r < 4; ++r){
    u16* dst = Qh + (size_t)(rt*64 + rq*4 + r)*HD + n0;
    *(ushort4*)dst = hpk4(acc[r*4+0]+bv.x, acc[r*4+1]+bv.y,
                          acc[r*4+2]+bv.z, acc[r*4+3]+bv.w);
  }
}

// ---------- S[b][l][t] = Q[b,l,:] . enc[b,t,:] ; grid (128 b, 8 tt), dot2 ----------
__global__ __launch_bounds__(256) void k_scores(const u16* __restrict__ Qh,
                                                const u16* __restrict__ enc,
                                                float* __restrict__ Sbuf){
  const int bI = blockIdx.x, tt = blockIdx.y;
  const int tid = threadIdx.x;
  __shared__ u32 A2_s[16*68];
  __shared__ u32 B2_s[16*68];
  const int lq = tid >> 4, tq = tid & 15;
  const int i = tid >> 2, jj = tid & 3;
  float acc[16] = {};
  for (int kc = 0; kc < 16; ++kc){
    __syncthreads();
    {
      uint4 va = *(const uint4*)(Qh + ((size_t)i*BB + bI)*HD + kc*32 + jj*8);
      A2_s[(jj*4+0)*68+i] = va.x;
      A2_s[(jj*4+1)*68+i] = va.y;
      A2_s[(jj*4+2)*68+i] = va.z;
      A2_s[(jj*4+3)*68+i] = va.w;
    }
    {
      uint4 vb = *(const uint4*)(enc + ((size_t)bI*TT + tt*64 + i)*HD + kc*32 + jj*8);
      B2_s[(jj*4+0)*68+i] = vb.x;
      B2_s[(jj*4+1)*68+i] = vb.y;
      B2_s[(jj*4+2)*68+i] = vb.z;
      B2_s[(jj*4+3)*68+i] = vb.w;
    }
    __syncthreads();
    INNER8P(lq, tq)
  }
  #pragma unroll
  for (int r = 0; r < 4; ++r){
    float4 o = make_float4(acc[r*4+0],acc[r*4+1],acc[r*4+2],acc[r*4+3]);
    *(float4*)&Sbuf[((size_t)bI*LL + lq*4+r)*TT + tt*64 + tq*4] = o;
  }
}

// ---------- row softmax over t: P f16 ; grid 8192 x 64 ----------
__global__ __launch_bounds__(64) void k_softmax(const float* __restrict__ Sbuf,
                                                u16* __restrict__ Ph){
  const int row = blockIdx.x;
  const int lane = threadIdx.x;
  const float* s = Sbuf + (size_t)row*TT;
  float v[8]; float m = -1e30f;
  #pragma unroll
  for (int i = 0; i < 8; ++i){ v[i] = s[lane + i*64]; m = fmaxf(m, v[i]); }
  #pragma unroll
  for (int o = 32; o; o >>= 1) m = fmaxf(m, __shfl_xor(m, o));
  float Z = 0.f;
  #pragma unroll
  for (int i = 0; i < 8; ++i){ v[i] = fexp2(1.4426950408889634f*(v[i] - m)); Z += v[i]; }
  #pragma unroll
  for (int o = 32; o; o >>= 1) Z += __shfl_xor(Z, o);
  float inv = frcp(Z);
  u16* p = Ph + (size_t)row*TT;
  #pragma unroll
  for (int i = 0; i < 8; ++i) p[lane + i*64] = f2h(v[i]*inv);
}

// ---------- attn[b][t][l] = f32(P[b][l][t]) ; grid (128 b, 8 tt) ----------
__global__ __launch_bounds__(256) void k_attn_tr(const u16* __restrict__ Ph,
                                                 float* __restrict__ att){
  const int bI = blockIdx.x, tt = blockIdx.y;
  const int tid = threadIdx.x;
  __shared__ u16 tile[64][72];
  {
    const int i = tid >> 2, jj = tid & 3;
    #pragma unroll
    for (int rep = 0; rep < 2; ++rep){
      int ch = jj + rep*4;
      uint4 v = *(const uint4*)(Ph + ((size_t)bI*LL + i)*TT + tt*64 + ch*8);
      *(uint4*)&tile[i][ch*8] = v;
    }
  }
  __syncthreads();
  const int t = tid >> 2, jl = tid & 3;
  #pragma unroll
  for (int rep = 0; rep < 4; ++rep){
    int l0 = jl*16 + rep*4;
    float4 o;
    o.x = h2f(tile[l0+0][t]); o.y = h2f(tile[l0+1][t]);
    o.z = h2f(tile[l0+2][t]); o.w = h2f(tile[l0+3][t]);
    *(float4*)&att[((size_t)bI*TT + tt*64 + t)*LL + l0] = o;
  }
}

// ---------- ctx[l*128+b][n] = P[b,l,:] @ enc[b,:,n] -> f16 ; grid (128 b, 8 nt) ----------
__global__ __launch_bounds__(256) void k_ctx(const u16* __restrict__ Ph,
                                             const u16* __restrict__ enc,
                                             u16* __restrict__ ctxh){
  const int bI = blockIdx.x, nt = blockIdx.y;
  const int tid = threadIdx.x;
  __shared__ float A_s[32*68];
  __shared__ float B_s[32*68];
  const int lq = tid >> 4, nq = tid & 15;
  const int i = tid >> 2, jj = tid & 3;
  const int i2 = tid >> 3, jj2 = tid & 7;
  float acc[16] = {};
  for (int tc = 0; tc < 16; ++tc){
    __syncthreads();
    {
      float tmp[8];
      uint4 va = *(const uint4*)(Ph + ((size_t)bI*LL + i)*TT + tc*32 + jj*8);
      unp8h(va, tmp);
      #pragma unroll
      for (int m = 0; m < 8; ++m) A_s[(jj*8+m)*68 + i] = tmp[m];
    }
    {
      float tmp[8];
      uint4 vb = *(const uint4*)(enc + ((size_t)bI*TT + tc*32 + i2)*HD + nt*64 + jj2*8);
      unp8h(vb, tmp);
      *(float4*)&B_s[i2*68 + jj2*8]     = make_float4(tmp[0],tmp[1],tmp[2],tmp[3]);
      *(float4*)&B_s[i2*68 + jj2*8 + 4] = make_float4(tmp[4],tmp[5],tmp[6],tmp[7]);
    }
    __syncthreads();
    INNER16(lq, nq)
  }
  const int n0 = nt*64 + nq*4;
  #pragma unroll
  for (int r = 0; r < 4; ++r){
    int ll = lq*4 + r;
    u16* dst = ctxh + ((size_t)ll*BB + bI)*HD + n0;
    *(ushort4*)dst = hpk4(acc[r*4+0], acc[r*4+1], acc[r*4+2], acc[r*4+3]);
  }
}

// ---------- o = [Hall|ctx] @ WcT + bc ; grid (128 rt, 4 nt), dot2 ----------
__global__ __launch_bounds__(256) void k_outc(const float* __restrict__ Hall,
                                              const u16* __restrict__ ctxh,
                                              const u32* __restrict__ Wc2,
                                              const float* __restrict__ bc,
                                              float* __restrict__ obuf){
  const int rt = blockIdx.x, nt = blockIdx.y;
  const int tid = threadIdx.x;
  __shared__ u32 A2_s[16*68];
  __shared__ u32 B2_s[16*68];
  const int rq = tid >> 4, nq = tid & 15;
  const int i = tid >> 2, jj = tid & 3;
  const int i3 = tid >> 4, n4 = tid & 15;
  float acc[16] = {};
  for (int kc = 0; kc < 32; ++kc){
    __syncthreads();
    if (kc < 16){
      const float* src = Hall + (size_t)(rt*64 + i)*HD + kc*32 + jj*8;
      float4 v0 = *(const float4*)src, v1 = *(const float4*)(src+4);
      A2_s[(jj*4+0)*68+i] = pkrtz(v0.x, v0.y);
      A2_s[(jj*4+1)*68+i] = pkrtz(v0.z, v0.w);
      A2_s[(jj*4+2)*68+i] = pkrtz(v1.x, v1.y);
      A2_s[(jj*4+3)*68+i] = pkrtz(v1.z, v1.w);
    } else {
      uint4 v = *(const uint4*)(ctxh + (size_t)(rt*64 + i)*HD + (kc-16)*32 + jj*8);
      A2_s[(jj*4+0)*68+i] = v.x;
      A2_s[(jj*4+1)*68+i] = v.y;
      A2_s[(jj*4+2)*68+i] = v.z;
      A2_s[(jj*4+3)*68+i] = v.w;
    }
    {
      uint4 v = *(const uint4*)(Wc2 + (size_t)(kc*16 + i3)*256 + nt*64 + n4*4);
      *(uint4*)&B2_s[i3*68 + n4*4] = v;
    }
    __syncthreads();
    INNER8P(rq, nq)
  }
  const int n0 = nt*64 + nq*4;
  float4 bv = *(const float4*)&bc[n0];
  #pragma unroll
  for (int r = 0; r < 4; ++r){
    float4 o = make_float4(acc[r*4+0]+bv.x, acc[r*4+1]+bv.y,
                           acc[r*4+2]+bv.z, acc[r*4+3]+bv.w);
    *(float4*)&obuf[(size_t)(rt*64 + rq*4 + r)*256 + n0] = o;
  }
}

// ---------- logits = o @ Wf^T + bf ; grid 128 ----------
__global__ __launch_bounds__(256) void k_fc(const float* __restrict__ obuf,
                                            const float* __restrict__ Wf,
                                            const float* __restrict__ bfv,
                                            float* __restrict__ out_vec){
  const int rt = blockIdx.x;
  const int tid = threadIdx.x;
  __shared__ float w_s[30*260];
  for (int rr = 0; rr < 30; ++rr) w_s[rr*260 + tid] = Wf[(size_t)rr*256 + tid];
  __syncthreads();
  const int rl = tid >> 2, dq = tid & 3;
  const int r = rt*64 + rl;
  float acc[8] = {};
  for (int k = 0; k < 256; k += 4){
    float4 o4 = *(const float4*)&obuf[(size_t)r*256 + k];
    #pragma unroll
    for (int jq = 0; jq < 8; ++jq){
      int d = dq*8 + jq;
      if (d < 30){
        float4 w4 = *(const float4*)&w_s[d*260 + k];
        acc[jq] = fmaf(o4.x,w4.x,fmaf(o4.y,w4.y,fmaf(o4.z,w4.z,fmaf(o4.w,w4.w,acc[jq]))));
      }
    }
  }
  const int b = r & 127, l = r >> 7;
  #pragma unroll
  for (int jq = 0; jq < 8; ++jq){
    int d = dq*8 + jq;
    if (d < 30) out_vec[((size_t)b*LL + l)*NDICT + d] = acc[jq] + bfv[d];
  }
}

__global__ __launch_bounds__(256) void k_copy(const float* __restrict__ src,
                                              float* __restrict__ dst, int n){
  int i = blockIdx.x*256 + threadIdx.x;
  if (i < n) dst[i] = src[i];
}

extern "C" void kernel_launch(void* const* d_in, const int* in_sizes, int n_in,
                              void* d_out, int out_size, void* d_ws, size_t ws_size,
                              hipStream_t stream)
{
  const float* x     = (const float*)d_in[0];
  const int*   tgt   = (const int*)  d_in[1];
  const float* eWihF = (const float*)d_in[2];
  const float* eWhhF = (const float*)d_in[3];
  const float* ebihF = (const float*)d_in[4];
  const float* ebhhF = (const float*)d_in[5];
  const float* eWihB = (const float*)d_in[6];
  const float* eWhhB = (const float*)d_in[7];
  const float* ebihB = (const float*)d_in[8];
  const float* ebhhB = (const float*)d_in[9];
  const float* emb   = (const float*)d_in[10];
  const float* dWih  = (const float*)d_in[11];
  const float* dWhh  = (const float*)d_in[12];
  const float* dbih  = (const float*)d_in[13];
  const float* dbhh  = (const float*)d_in[14];
  const float* Wq    = (const float*)d_in[15];
  const float* bq    = (const float*)d_in[16];
  const float* Wc    = (const float*)d_in[17];
  const float* bc    = (const float*)d_in[18];
  const float* Wf    = (const float*)d_in[19];
  const float* bfv   = (const float*)d_in[20];

  char* w = (char*)d_ws;
  uint4* Wpenc = (uint4*)w; w += 786432;     // [2][32][768] uint4 f16 tile layout
  uint4* Wpdec = (uint4*)w; w += 1572864;    // [64][24][64] uint4 f16 M-parallel
  u32*   Wq2   = (u32*)w;  w += 524288;      // [256 kp][512 n] f16 pairs
  u32*   Wc2   = (u32*)w;  w += 524288;      // [512 kp][256 n] f16 pairs
  float* gi_t  = (float*)w; w += 184320;
  float* h0buf = (float*)w; w += 262144;
  f16*   h16A  = (f16*)w; w += 131072;       // [128][512] f16
  f16*   h16B  = (f16*)w; w += 131072;
  float* Hall  = (float*)w; w += 16777216;
  u16*   Qh    = (u16*)w;                    // aliased: Ph reuses after k_scores
  u16*   Ph    = (u16*)w; w += 8388608;
  float* Sbuf  = (float*)w;                  // aliased over (ctxh | obuf)
  u16*   ctxh  = (u16*)w; w += 8388608;
  float* obuf  = (float*)w; w += 8388608;
  u16*   ench  = (u16*)w; w += 67108864;

  float* out     = (float*)d_out;
  float* out_vec = out;                              // [128][64][30]
  float* out_hT  = out + (size_t)BB*LL*NDICT;        // [1][128][512]
  float* out_att = out_hT + (size_t)BB*HD;           // [128][512][64]

  // prep
  k_prep_wenc<<<192, 256, 0, stream>>>(eWhhF, eWhhB, Wpenc);
  k_prep_wdec<<<384, 256, 0, stream>>>(dWhh, Wpdec);
  k_prep_pairT<<<512, 256, 0, stream>>>(Wq, Wq2, HD, HD);
  k_prep_pairT<<<512, 256, 0, stream>>>(Wc, Wc2, 256, 1024);
  k_gi_tab<<<dim3(NDICT, 6), 256, 0, stream>>>(emb, dWih, dbih, gi_t);

  // encoder: 256 independent recurrences, col-split dot + shfl butterfly
  k_enc_p<<<BB*2, G3E, 0, stream>>>(x, Wpenc, eWihF, eWihB,
                                    ebihF, ebhhF, ebihB, ebhhB, ench, h0buf);

  // decoder recurrence: one launch per step, M-parallel, conflict-free LDS
  k_h0cvt<<<256, 256, 0, stream>>>(h0buf, h16A);
  for (int l = 0; l < LL; ++l){
    const f16* hp = (l & 1) ? h16B : h16A;
    f16*       hn = (l & 1) ? h16A : h16B;
    k_dstep<<<512, 256, 0, stream>>>(tgt, gi_t, Wpdec, dbhh, hp, hn, Hall, l);
  }

  // batched post-recurrence pipeline
  k_query<<<dim3(128,8), 256, 0, stream>>>(Hall, Wq2, bq, Qh);
  k_scores<<<dim3(128,8), 256, 0, stream>>>(Qh, ench, Sbuf);
  k_softmax<<<BB*LL, 64, 0, stream>>>(Sbuf, Ph);
  k_attn_tr<<<dim3(128,8), 256, 0, stream>>>(Ph, out_att);
  k_ctx<<<dim3(128,8), 256, 0, stream>>>(Ph, ench, ctxh);
  k_outc<<<dim3(128,4), 256, 0, stream>>>(Hall, ctxh, Wc2, bc, obuf);
  k_fc<<<BB, 256, 0, stream>>>(obuf, Wf, bfv, out_vec);
  k_copy<<<(BB*HD+255)/256, 256, 0, stream>>>(Hall + (size_t)63*BB*HD, out_hT, BB*HD);
}